// Round 1
// baseline (854.041 us; speedup 1.0000x reference)
//
#include <hip/hip_runtime.h>

#define PP 256
#define BB 32
#define MM 1024
#define NN 1024

constexpr float EPSF = 1e-5f;

// ---------------------------------------------------------------------------
// Tiled f32 GEMM: C[b][r][n] = sum_k Aelem(b,r,k) * Bw[b][k][n]
//   Aelem = ATRANS ? Ab[k*lda + r] : Ab[r*lda + k]
// Tile 64x64, BK=16, 256 threads, 4x4 per thread. N-dim (cols) is always 256.
// ---------------------------------------------------------------------------
template<bool ATRANS>
__global__ __launch_bounds__(256)
void gemm_f32(const float* __restrict__ A, long aStride, int lda,
              const float* __restrict__ Bw, long bStride,
              float* __restrict__ C, long cStride,
              int K)
{
  const int b = blockIdx.z;
  const float* __restrict__ Ab = A + (long)b * aStride;
  const float* __restrict__ Bb = Bw + (long)b * bStride;
  float* __restrict__ Cb = C + (long)b * cStride;

  const int r0 = blockIdx.x * 64;
  const int n0 = blockIdx.y * 64;

  __shared__ float As[16][64];   // [k][m]
  __shared__ float Bs[16][64];   // [k][n]

  const int tid = threadIdx.x;
  const int tx = tid & 15, ty = tid >> 4;

  float acc[4][4] = {};

  for (int k0 = 0; k0 < K; k0 += 16) {
    if (!ATRANS) {
      // A row-major: each thread loads float4 along k, stores transposed
      const int r  = tid >> 2;
      const int kq = (tid & 3) << 2;
      float4 av = *reinterpret_cast<const float4*>(&Ab[(long)(r0 + r) * lda + (k0 + kq)]);
      As[kq + 0][r] = av.x;
      As[kq + 1][r] = av.y;
      As[kq + 2][r] = av.z;
      As[kq + 3][r] = av.w;
    } else {
      // A column-major access (per-batch transpose): rows are contiguous in r
      const int kk = tid >> 4;
      const int r4 = (tid & 15) << 2;
      float4 av = *reinterpret_cast<const float4*>(&Ab[(long)(k0 + kk) * lda + (r0 + r4)]);
      *reinterpret_cast<float4*>(&As[kk][r4]) = av;
    }
    {
      const int kk = tid >> 4;
      const int n4 = (tid & 15) << 2;
      float4 bv = *reinterpret_cast<const float4*>(&Bb[(long)(k0 + kk) * PP + (n0 + n4)]);
      *reinterpret_cast<float4*>(&Bs[kk][n4]) = bv;
    }
    __syncthreads();
#pragma unroll
    for (int kk = 0; kk < 16; ++kk) {
      float4 a  = *reinterpret_cast<const float4*>(&As[kk][ty << 2]);
      float4 bv = *reinterpret_cast<const float4*>(&Bs[kk][tx << 2]);
      const float av[4] = {a.x, a.y, a.z, a.w};
      const float bw[4] = {bv.x, bv.y, bv.z, bv.w};
#pragma unroll
      for (int i = 0; i < 4; ++i)
#pragma unroll
        for (int j = 0; j < 4; ++j)
          acc[i][j] = fmaf(av[i], bw[j], acc[i][j]);
    }
    __syncthreads();
  }
#pragma unroll
  for (int i = 0; i < 4; ++i) {
    float4 v = make_float4(acc[i][0], acc[i][1], acc[i][2], acc[i][3]);
    *reinterpret_cast<float4*>(&Cb[(long)(r0 + (ty << 2) + i) * PP + n0 + (tx << 2)]) = v;
  }
}

// ---------------------------------------------------------------------------
// Column-sum partials: src [B][1024][256] -> part [B][16][256] (sum of 64 rows)
// ---------------------------------------------------------------------------
__global__ __launch_bounds__(256)
void colsum_partial(const float* __restrict__ src, float* __restrict__ part)
{
  const int p = threadIdx.x;
  const int c = blockIdx.x;   // 16 chunks
  const int b = blockIdx.y;
  const float* s = src + ((long)b * 1024 + (long)c * 64) * 256 + p;
  float acc = 0.f;
#pragma unroll 4
  for (int m = 0; m < 64; ++m) acc += s[m * 256];
  part[((long)b * 16 + c) * 256 + p] = acc;
}

// block of 256 threads: reduce (v1,v2) across block; result broadcast to all
__device__ inline void block_reduce2(float& v1, float& v2, float* red)
{
#pragma unroll
  for (int off = 32; off > 0; off >>= 1) {
    v1 += __shfl_down(v1, off);
    v2 += __shfl_down(v2, off);
  }
  const int lane = threadIdx.x & 63, wid = threadIdx.x >> 6;
  if (lane == 0) { red[wid * 2] = v1; red[wid * 2 + 1] = v2; }
  __syncthreads();
  v1 = red[0] + red[2] + red[4] + red[6];
  v2 = red[1] + red[3] + red[5] + red[7];
}

// combine partials, normalize over P (ddof=1), * gamma + beta + 1
__global__ __launch_bounds__(256)
void norm_sum(const float* __restrict__ part, const float* __restrict__ gamma,
              const float* __restrict__ beta, float* __restrict__ out)
{
  const int b = blockIdx.x;
  const int p = threadIdx.x;
  float s = 0.f;
#pragma unroll
  for (int c = 0; c < 16; ++c) s += part[((long)b * 16 + c) * 256 + p];
  __shared__ float red[8];
  float v1 = s, v2 = s * s;
  block_reduce2(v1, v2, red);
  const float mean = v1 / 256.0f;
  float var = (v2 - v1 * mean) / 255.0f;
  var = fmaxf(var, 0.f);
  const float inv = 1.0f / (sqrtf(var) + EPSF);
  out[(long)b * 256 + p] = gamma[p] * (s - mean) * inv + beta[p] + 1.0f;
}

// mean + 1/(std+eps) over 256x256 elements per batch (ddof=1)
__global__ __launch_bounds__(256)
void stats_pp(const float* __restrict__ src, float* __restrict__ st)
{
  const int b = blockIdx.x;
  const float* s = src + ((long)b << 16);
  float v1 = 0.f, v2 = 0.f;
  for (int i = threadIdx.x; i < 65536; i += 256) {
    const float x = s[i];
    v1 += x;
    v2 = fmaf(x, x, v2);
  }
  __shared__ float red[8];
  block_reduce2(v1, v2, red);
  if (threadIdx.x == 0) {
    const float mean = v1 / 65536.0f;
    float var = (v2 - v1 * mean) / 65535.0f;
    var = fmaxf(var, 0.f);
    st[b * 2]     = mean;
    st[b * 2 + 1] = 1.0f / (sqrtf(var) + EPSF);
  }
}

// Ap[b,i,j] = norm_o(t2[b,j,i]) * rel;  Bp[b,i,j] = norm_p(p2[b,j,i]) * rel
// rel = o_sum[b,i] * p_sum[b,j]
__global__ __launch_bounds__(256)
void prep(const float* __restrict__ t2, const float* __restrict__ p2,
          const float* __restrict__ o_sum, const float* __restrict__ p_sum,
          const float* __restrict__ gamma_o, const float* __restrict__ beta_o,
          const float* __restrict__ gamma_p, const float* __restrict__ beta_p,
          const float* __restrict__ stO, const float* __restrict__ stP,
          float* __restrict__ Ap, float* __restrict__ Bp)
{
  const long idx = (long)blockIdx.x * 256 + threadIdx.x;   // over B*P*P
  const int b  = (int)(idx >> 16);
  const int ij = (int)(idx & 65535);
  const int i = ij >> 8, j = ij & 255;
  const long tpos = ((long)b << 16) + ((long)j << 8) + i;  // transposed read
  const float on = gamma_o[ij] * (t2[tpos] - stO[b * 2]) * stO[b * 2 + 1] + beta_o[ij];
  const float pn = gamma_p[ij] * (p2[tpos] - stP[b * 2]) * stP[b * 2 + 1] + beta_p[ij];
  const float rel = o_sum[(b << 8) + i] * p_sum[(b << 8) + j];
  Ap[idx] = on * rel;
  Bp[idx] = pn * rel;
}

// out[0..B*P*P) = normalized projected; out[B*P*P..) = relations
__global__ __launch_bounds__(256)
void final_write(const float* __restrict__ proj, const float* __restrict__ stF,
                 const float* __restrict__ gamma, const float* __restrict__ beta,
                 const float* __restrict__ o_sum, const float* __restrict__ p_sum,
                 float* __restrict__ out)
{
  const long idx = (long)blockIdx.x * 256 + threadIdx.x;
  const int b  = (int)(idx >> 16);
  const int ij = (int)(idx & 65535);
  const int i = ij >> 8, j = ij & 255;
  out[idx] = gamma[ij] * (proj[idx] - stF[b * 2]) * stF[b * 2 + 1] + beta[ij];
  out[(long)BB * 65536 + idx] = o_sum[(b << 8) + i] * p_sum[(b << 8) + j];
}

extern "C" void kernel_launch(void* const* d_in, const int* in_sizes, int n_in,
                              void* d_out, int out_size, void* d_ws, size_t ws_size,
                              hipStream_t stream)
{
  const float* x    = (const float*)d_in[0];
  const float* Wo1  = (const float*)d_in[1];   // original_xj_y [N,P]
  const float* Wo2  = (const float*)d_in[2];   // original_xi_y [M,P]
  const float* Wp1  = (const float*)d_in[3];   // permuted_xj_y [M,P]
  const float* Wp2  = (const float*)d_in[4];   // permuted_xi_y [N,P]
  const float* g_os = (const float*)d_in[5];
  const float* g_o  = (const float*)d_in[6];
  const float* g_ps = (const float*)d_in[7];
  const float* g_p  = (const float*)d_in[8];
  const float* g    = (const float*)d_in[9];
  const float* b_os = (const float*)d_in[10];
  const float* b_o  = (const float*)d_in[11];
  const float* b_ps = (const float*)d_in[12];
  const float* b_p  = (const float*)d_in[13];
  const float* b_   = (const float*)d_in[14];
  float* out = (float*)d_out;

  float* ws = (float*)d_ws;
  float* oyy    = ws;                       // 8388608 floats [B,M,P]
  float* pyy    = oyy + 8388608;            // 8388608 [B,N,P]
  float* t2     = pyy + 8388608;            // 2097152 [B,P,P]
  float* p2     = t2 + 2097152;             // 2097152
  float* o_part = p2 + 2097152;             // 131072
  float* p_part = o_part + 131072;          // 131072
  float* o_sum  = p_part + 131072;          // 8192
  float* p_sum  = o_sum + 8192;             // 8192
  float* stO    = p_sum + 8192;             // 64
  float* stP    = stO + 64;                 // 64
  float* stF    = stP + 64;                 // 64
  // alias: oyy/pyy dead after G3/G4 -> reuse oyy region
  float* Ap   = oyy;                        // 2097152
  float* Bp   = oyy + 2097152;              // 2097152
  float* proj = oyy + 4194304;              // 2097152

  // G1: oyy[b,m,p] = sum_n x[b,m,n] * Wo1[n,p]
  hipLaunchKernelGGL((gemm_f32<false>), dim3(16, 4, 32), dim3(256), 0, stream,
                     x, (long)MM * NN, NN, Wo1, 0L, oyy, (long)MM * PP, NN);
  // G2: pyy[b,n,p] = sum_m x[b,m,n] * Wp1[m,p]   (A transposed per batch)
  hipLaunchKernelGGL((gemm_f32<true>), dim3(16, 4, 32), dim3(256), 0, stream,
                     x, (long)MM * NN, NN, Wp1, 0L, pyy, (long)NN * PP, MM);

  colsum_partial<<<dim3(16, 32), 256, 0, stream>>>(oyy, o_part);
  colsum_partial<<<dim3(16, 32), 256, 0, stream>>>(pyy, p_part);
  norm_sum<<<32, 256, 0, stream>>>(o_part, g_os, b_os, o_sum);
  norm_sum<<<32, 256, 0, stream>>>(p_part, g_ps, b_ps, p_sum);

  // G3: t2[b,p,q] = sum_m oyy[b,m,p] * Wo2[m,q]
  hipLaunchKernelGGL((gemm_f32<true>), dim3(4, 4, 32), dim3(256), 0, stream,
                     oyy, (long)MM * PP, PP, Wo2, 0L, t2, (long)PP * PP, MM);
  // G4: p2[b,p,q] = sum_n pyy[b,n,p] * Wp2[n,q]
  hipLaunchKernelGGL((gemm_f32<true>), dim3(4, 4, 32), dim3(256), 0, stream,
                     pyy, (long)NN * PP, PP, Wp2, 0L, p2, (long)PP * PP, NN);

  stats_pp<<<32, 256, 0, stream>>>(t2, stO);
  stats_pp<<<32, 256, 0, stream>>>(p2, stP);

  prep<<<8192, 256, 0, stream>>>(t2, p2, o_sum, p_sum, g_o, b_o, g_p, b_p, stO, stP, Ap, Bp);

  // G5: proj[b,i,j] = sum_k Ap[b,i,k] * Bp[b,k,j]
  hipLaunchKernelGGL((gemm_f32<false>), dim3(4, 4, 32), dim3(256), 0, stream,
                     Ap, (long)PP * PP, PP, Bp, (long)PP * PP, proj, (long)PP * PP, PP);

  stats_pp<<<32, 256, 0, stream>>>(proj, stF);
  final_write<<<8192, 256, 0, stream>>>(proj, stF, g, b_, o_sum, p_sum, out);
}

// Round 2
// 241.438 us; speedup vs baseline: 3.5373x; 3.5373x over previous
//
#include <hip/hip_runtime.h>
#include <hip/hip_bf16.h>

#define PP 256
#define BB 32
#define MM 1024
#define NN 1024

constexpr float EPSF = 1e-5f;

typedef __attribute__((ext_vector_type(8))) short short8v;
typedef __attribute__((ext_vector_type(4))) short short4v;
typedef __attribute__((ext_vector_type(4))) float f32x4;

__device__ inline float bf2f(short s) {
  union { unsigned u; float f; } cv;
  cv.u = ((unsigned)(unsigned short)s) << 16;
  return cv.f;
}
__device__ inline short f2bf(float f) {
  union { float f; unsigned u; } cv; cv.f = f;
  unsigned u = cv.u;
  unsigned r = (u + 0x7fffu + ((u >> 16) & 1u)) >> 16;
  return (short)r;
}

__device__ inline void gload16(const void* g, void* l) {
  __builtin_amdgcn_global_load_lds(
      (const __attribute__((address_space(1))) unsigned*)g,
      (__attribute__((address_space(3))) unsigned*)l, 16, 0, 0);
}

// ---------------------------------------------------------------------------
// Transpose/convert f32 [R][C] -> bf16 [R][C] (plain) and/or bf16 [C][R]
// ---------------------------------------------------------------------------
template<bool WP, bool WT>
__global__ __launch_bounds__(256)
void convert_tr(const float* __restrict__ src, long sStride, int R, int C,
                short* __restrict__ dstP, long pStride,
                short* __restrict__ dstT, long tStride)
{
  __shared__ float tile[64][65];
  const int b = blockIdx.z;
  const int c0 = blockIdx.x * 64, r0 = blockIdx.y * 64;
  const float* s = src + (long)b * sStride;
  const int tid = threadIdx.x;
#pragma unroll
  for (int i = 0; i < 16; ++i) {
    int idx = i * 256 + tid;
    int r = idx >> 6, c = idx & 63;
    tile[r][c] = s[(long)(r0 + r) * C + (c0 + c)];
  }
  __syncthreads();
  if (WP) {
    short* d = dstP + (long)b * pStride;
#pragma unroll
    for (int i = 0; i < 16; ++i) {
      int idx = i * 256 + tid;
      int r = idx >> 6, c = idx & 63;
      d[(long)(r0 + r) * C + (c0 + c)] = f2bf(tile[r][c]);
    }
  }
  if (WT) {
    short* d = dstT + (long)b * tStride;
#pragma unroll
    for (int i = 0; i < 16; ++i) {
      int idx = i * 256 + tid;
      int rr = idx >> 6, cc = idx & 63;
      d[(long)(c0 + rr) * R + (r0 + cc)] = f2bf(tile[cc][rr]);
    }
  }
}

// f32 [R][C] -> f32 [C][R]
__global__ __launch_bounds__(256)
void transpose_f32(const float* __restrict__ src, float* __restrict__ dst,
                   int R, int C)
{
  __shared__ float tile[64][65];
  const int c0 = blockIdx.x * 64, r0 = blockIdx.y * 64;
  const int tid = threadIdx.x;
#pragma unroll
  for (int i = 0; i < 16; ++i) {
    int idx = i * 256 + tid;
    int r = idx >> 6, c = idx & 63;
    tile[r][c] = src[(long)(r0 + r) * C + (c0 + c)];
  }
  __syncthreads();
#pragma unroll
  for (int i = 0; i < 16; ++i) {
    int idx = i * 256 + tid;
    int rr = idx >> 6, cc = idx & 63;
    dst[(long)(c0 + rr) * R + (r0 + cc)] = tile[cc][rr];
  }
}

// ---------------------------------------------------------------------------
// bf16 MFMA GEMM.  A: [rows][K] bf16 k-contig.  BT: [cols][K] bf16 k-contig.
// C = A * BT^T.  OUTMODE: 0 = f32 normal [M][N] (ldc=N);
//                         1 = f32 C^T [N][M] (ldc=M);
//                         2 = bf16 C^T [N][M] (ldc=M)
// LDS layout: slot s = kc*BR + r holds 8 bf16 (k = k0+kc*8 .. +8) of row r.
// ---------------------------------------------------------------------------
enum { OUT_F32 = 0, OUT_CT_F32 = 1, OUT_CT_BF16 = 2 };

template<int BM, int BN, int WM, int WN, int OUTMODE>
__global__ __launch_bounds__(256)
void gemm_bf16(const short* __restrict__ A, long aStride,
               const short* __restrict__ BT, long bStride,
               void* __restrict__ Cout, long cStride,
               int K, int ldc)
{
  constexpr int BK = 32;
  constexpr int KC = 4;               // 4 k-chunks of 8
  constexpr int WAVES_N = BN / WN;
  constexpr int FM = WM / 16, FN = WN / 16;
  static_assert((BM / WM) * (BN / WN) == 4, "4 waves");
  __shared__ short As[KC * BM * 8];
  __shared__ short Bs[KC * BN * 8];

  const int b = blockIdx.z;
  const short* Ab = A + (long)b * aStride;
  const short* Bb = BT + (long)b * bStride;
  const int m0 = blockIdx.x * BM, n0 = blockIdx.y * BN;

  const int tid = threadIdx.x;
  const int l = tid & 63, w = tid >> 6;
  const int wr = w / WAVES_N, wc = w % WAVES_N;
  const int lk = l >> 4, lr = l & 15;

  f32x4 acc[FM][FN];
#pragma unroll
  for (int fm = 0; fm < FM; ++fm)
#pragma unroll
    for (int fn = 0; fn < FN; ++fn)
      acc[fm][fn] = (f32x4){0.f, 0.f, 0.f, 0.f};

  constexpr int A_IT = (KC * BM) / 256;
  constexpr int B_IT = (KC * BN) / 256;

  for (int k0 = 0; k0 < K; k0 += BK) {
#pragma unroll
    for (int i = 0; i < A_IT; ++i) {
      int s = i * 256 + tid;
      int kc = s / BM, m = s % BM;
      gload16(Ab + (long)(m0 + m) * K + k0 + kc * 8, &As[s * 8]);
    }
#pragma unroll
    for (int i = 0; i < B_IT; ++i) {
      int s = i * 256 + tid;
      int kc = s / BN, n = s % BN;
      gload16(Bb + (long)(n0 + n) * K + k0 + kc * 8, &Bs[s * 8]);
    }
    __syncthreads();

    short8v af[FM], bf[FN];
#pragma unroll
    for (int fm = 0; fm < FM; ++fm)
      af[fm] = *(const short8v*)&As[(lk * BM + wr * WM + fm * 16 + lr) * 8];
#pragma unroll
    for (int fn = 0; fn < FN; ++fn)
      bf[fn] = *(const short8v*)&Bs[(lk * BN + wc * WN + fn * 16 + lr) * 8];
#pragma unroll
    for (int fm = 0; fm < FM; ++fm)
#pragma unroll
      for (int fn = 0; fn < FN; ++fn)
        acc[fm][fn] = __builtin_amdgcn_mfma_f32_16x16x32_bf16(
            af[fm], bf[fn], acc[fm][fn], 0, 0, 0);
    __syncthreads();
  }

  // Epilogue.  C/D frag: col = lr, rows = lk*4 + j  (verified m89/m91 layout)
  if (OUTMODE == OUT_F32) {
    float* Cb = (float*)Cout + (long)b * cStride;
#pragma unroll
    for (int fm = 0; fm < FM; ++fm)
#pragma unroll
      for (int fn = 0; fn < FN; ++fn) {
        const int c = n0 + wc * WN + fn * 16 + lr;
        const int rb = m0 + wr * WM + fm * 16 + lk * 4;
#pragma unroll
        for (int j = 0; j < 4; ++j)
          Cb[(long)(rb + j) * ldc + c] = acc[fm][fn][j];
      }
  } else if (OUTMODE == OUT_CT_F32) {
    float* Cb = (float*)Cout + (long)b * cStride;
#pragma unroll
    for (int fm = 0; fm < FM; ++fm)
#pragma unroll
      for (int fn = 0; fn < FN; ++fn) {
        const int c = n0 + wc * WN + fn * 16 + lr;
        const int rb = m0 + wr * WM + fm * 16 + lk * 4;
        *(f32x4*)&Cb[(long)c * ldc + rb] = acc[fm][fn];
      }
  } else {
    short* Cb = (short*)Cout + (long)b * cStride;
#pragma unroll
    for (int fm = 0; fm < FM; ++fm)
#pragma unroll
      for (int fn = 0; fn < FN; ++fn) {
        const int c = n0 + wc * WN + fn * 16 + lr;
        const int rb = m0 + wr * WM + fm * 16 + lk * 4;
        short4v pk;
#pragma unroll
        for (int j = 0; j < 4; ++j) pk[j] = f2bf(acc[fm][fn][j]);
        *(short4v*)&Cb[(long)c * ldc + rb] = pk;
      }
  }
}

// ---------------------------------------------------------------------------
// Row sums of bf16 [B][256][1024] (one wave per row) -> raw[b][256]
// ---------------------------------------------------------------------------
__global__ __launch_bounds__(256)
void colsum_bf16(const short* __restrict__ srcT, float* __restrict__ raw)
{
  const int b = blockIdx.y;
  const int w = threadIdx.x >> 6, l = threadIdx.x & 63;
  const int p = blockIdx.x * 4 + w;
  const short* row = srcT + ((long)b * 256 + p) * 1024;
  short8v v1 = *(const short8v*)&row[l * 8];
  short8v v2 = *(const short8v*)&row[(64 + l) * 8];
  float s = 0.f;
#pragma unroll
  for (int j = 0; j < 8; ++j) s += bf2f(v1[j]) + bf2f(v2[j]);
#pragma unroll
  for (int off = 32; off; off >>= 1) s += __shfl_down(s, off);
  if (l == 0) raw[(long)b * 256 + p] = s;
}

__device__ inline void block_reduce2(float& v1, float& v2, float* red)
{
#pragma unroll
  for (int off = 32; off > 0; off >>= 1) {
    v1 += __shfl_down(v1, off);
    v2 += __shfl_down(v2, off);
  }
  const int lane = threadIdx.x & 63, wid = threadIdx.x >> 6;
  if (lane == 0) { red[wid * 2] = v1; red[wid * 2 + 1] = v2; }
  __syncthreads();
  v1 = red[0] + red[2] + red[4] + red[6];
  v2 = red[1] + red[3] + red[5] + red[7];
}

__global__ __launch_bounds__(256)
void norm_sum(const float* __restrict__ raw, const float* __restrict__ gamma,
              const float* __restrict__ beta, float* __restrict__ out)
{
  const int b = blockIdx.x;
  const int p = threadIdx.x;
  float s = raw[(long)b * 256 + p];
  __shared__ float red[8];
  float v1 = s, v2 = s * s;
  block_reduce2(v1, v2, red);
  const float mean = v1 / 256.0f;
  float var = fmaxf((v2 - v1 * mean) / 255.0f, 0.f);
  const float inv = 1.0f / (sqrtf(var) + EPSF);
  out[(long)b * 256 + p] = gamma[p] * (s - mean) * inv + beta[p] + 1.0f;
}

// stats over 256x256 per batch, two-stage.  part[b][8][2]
__global__ __launch_bounds__(256)
void stats_part(const float* __restrict__ src, float* __restrict__ part)
{
  const int b = blockIdx.y, chunk = blockIdx.x;
  const float* s = src + ((long)b << 16) + (long)chunk * 8192;
  float v1 = 0.f, v2 = 0.f;
  for (int i = threadIdx.x; i < 2048; i += 256) {
    float4 x = *reinterpret_cast<const float4*>(&s[i * 4]);
    v1 += x.x + x.y + x.z + x.w;
    v2 = fmaf(x.x, x.x, fmaf(x.y, x.y, fmaf(x.z, x.z, fmaf(x.w, x.w, v2))));
  }
  __shared__ float red[8];
  block_reduce2(v1, v2, red);
  if (threadIdx.x == 0) {
    part[(b * 8 + chunk) * 2] = v1;
    part[(b * 8 + chunk) * 2 + 1] = v2;
  }
}

__global__ void stats_fin(const float* __restrict__ part, float* __restrict__ st)
{
  const int b = threadIdx.x;
  if (b < 32) {
    float v1 = 0.f, v2 = 0.f;
#pragma unroll
    for (int c = 0; c < 8; ++c) {
      v1 += part[(b * 8 + c) * 2];
      v2 += part[(b * 8 + c) * 2 + 1];
    }
    const float mean = v1 / 65536.0f;
    const float var = fmaxf((v2 - v1 * mean) / 65535.0f, 0.f);
    st[b * 2] = mean;
    st[b * 2 + 1] = 1.0f / (sqrtf(var) + EPSF);
  }
}

// Ap[b,r,c] = norm_o(t2T[b,r,c]) * o_sum[r]*p_sum[c]        (bf16)
// BpT[b,r,c] = norm_p(gTp,p2[b,r,c]) * o_sum[c]*p_sum[r]    (bf16)
__global__ __launch_bounds__(256)
void prep2(const float* __restrict__ t2T, const float* __restrict__ p2,
           const float* __restrict__ o_sum, const float* __restrict__ p_sum,
           const float* __restrict__ gamma_o, const float* __restrict__ beta_o,
           const float* __restrict__ gTp, const float* __restrict__ bTp,
           const float* __restrict__ stO, const float* __restrict__ stP,
           short* __restrict__ Ap, short* __restrict__ BpT)
{
  const long idx = (long)blockIdx.x * 256 + threadIdx.x;
  const int b = (int)(idx >> 16);
  const int rc = (int)(idx & 65535);
  const int r = rc >> 8, c = rc & 255;
  const float mO = stO[b * 2], iO = stO[b * 2 + 1];
  const float mP = stP[b * 2], iP = stP[b * 2 + 1];
  const float on = gamma_o[rc] * (t2T[idx] - mO) * iO + beta_o[rc];
  Ap[idx] = f2bf(on * o_sum[(b << 8) + r] * p_sum[(b << 8) + c]);
  const float pn = gTp[rc] * (p2[idx] - mP) * iP + bTp[rc];
  BpT[idx] = f2bf(pn * o_sum[(b << 8) + c] * p_sum[(b << 8) + r]);
}

__global__ __launch_bounds__(256)
void final_write(const float* __restrict__ proj, const float* __restrict__ stF,
                 const float* __restrict__ gamma, const float* __restrict__ beta,
                 const float* __restrict__ o_sum, const float* __restrict__ p_sum,
                 float* __restrict__ out)
{
  const long idx = (long)blockIdx.x * 256 + threadIdx.x;
  const int b = (int)(idx >> 16);
  const int ij = (int)(idx & 65535);
  const int i = ij >> 8, j = ij & 255;
  out[idx] = gamma[ij] * (proj[idx] - stF[b * 2]) * stF[b * 2 + 1] + beta[ij];
  out[(long)BB * 65536 + idx] = o_sum[(b << 8) + i] * p_sum[(b << 8) + j];
}

extern "C" void kernel_launch(void* const* d_in, const int* in_sizes, int n_in,
                              void* d_out, int out_size, void* d_ws, size_t ws_size,
                              hipStream_t stream)
{
  const float* x    = (const float*)d_in[0];
  const float* Wo1  = (const float*)d_in[1];
  const float* Wo2  = (const float*)d_in[2];
  const float* Wp1  = (const float*)d_in[3];
  const float* Wp2  = (const float*)d_in[4];
  const float* g_os = (const float*)d_in[5];
  const float* g_o  = (const float*)d_in[6];
  const float* g_ps = (const float*)d_in[7];
  const float* g_p  = (const float*)d_in[8];
  const float* g    = (const float*)d_in[9];
  const float* b_os = (const float*)d_in[10];
  const float* b_o  = (const float*)d_in[11];
  const float* b_ps = (const float*)d_in[12];
  const float* b_p  = (const float*)d_in[13];
  const float* b_   = (const float*)d_in[14];
  float* out = (float*)d_out;

  // ---- workspace layout (bf16 buffers as short*) ----
  short* xb   = (short*)d_ws;            // 33,554,432 sh  [B][M][N]
  short* xbT  = xb + 33554432;           // 33,554,432 sh  [B][N][M]
  short* wo1T = xbT + 33554432;          // 262,144 sh each, [P][K]
  short* wo2T = wo1T + 262144;
  short* wp1T = wo2T + 262144;
  short* wp2T = wp1T + 262144;
  short* oyyT = wp2T + 262144;           // 8,388,608 sh  [B][P][M]
  short* pyyT = oyyT + 8388608;          // 8,388,608 sh  [B][P][N]
  float* gTp  = (float*)(pyyT + 8388608);// 65,536 f
  float* bTp  = gTp + 65536;             // 65,536 f
  // phase-2 overlays the (dead after G1/G2) xb region:
  float* t2T  = (float*)xb;              // 2,097,152 f   [B][P][P]
  float* p2   = t2T + 2097152;           // 2,097,152 f
  float* proj = p2 + 2097152;            // 2,097,152 f
  short* Ap   = (short*)(proj + 2097152);// 2,097,152 sh
  short* BpT  = Ap + 2097152;            // 2,097,152 sh
  float* rawO = (float*)(BpT + 2097152); // 8192
  float* rawP = rawO + 8192;
  float* o_sum = rawP + 8192;            // 8192
  float* p_sum = o_sum + 8192;
  float* part  = p_sum + 8192;           // 512
  float* stO   = part + 512;             // 64
  float* stP   = stO + 64;
  float* stF   = stP + 64;

  // ---- conversions ----
  hipLaunchKernelGGL((convert_tr<true, true>), dim3(16, 16, 32), dim3(256), 0, stream,
                     x, (long)MM * NN, MM, NN, xb, (long)MM * NN, xbT, (long)MM * NN);
  hipLaunchKernelGGL((convert_tr<false, true>), dim3(4, 16, 1), dim3(256), 0, stream,
                     Wo1, 0L, 1024, 256, nullptr, 0L, wo1T, 0L);
  hipLaunchKernelGGL((convert_tr<false, true>), dim3(4, 16, 1), dim3(256), 0, stream,
                     Wo2, 0L, 1024, 256, nullptr, 0L, wo2T, 0L);
  hipLaunchKernelGGL((convert_tr<false, true>), dim3(4, 16, 1), dim3(256), 0, stream,
                     Wp1, 0L, 1024, 256, nullptr, 0L, wp1T, 0L);
  hipLaunchKernelGGL((convert_tr<false, true>), dim3(4, 16, 1), dim3(256), 0, stream,
                     Wp2, 0L, 1024, 256, nullptr, 0L, wp2T, 0L);
  transpose_f32<<<dim3(4, 4), 256, 0, stream>>>(g_p, gTp, 256, 256);
  transpose_f32<<<dim3(4, 4), 256, 0, stream>>>(b_p, bTp, 256, 256);

  // ---- G1: oyyT[b][p][m] = (xb @ Wo1)^T ----
  hipLaunchKernelGGL((gemm_bf16<128, 128, 64, 64, OUT_CT_BF16>), dim3(8, 2, 32), dim3(256), 0, stream,
                     xb, (long)MM * NN, wo1T, 0L, oyyT, (long)PP * MM, NN, MM);
  // ---- G2: pyyT[b][p][n] = (x^T @ Wp1)^T ----
  hipLaunchKernelGGL((gemm_bf16<128, 128, 64, 64, OUT_CT_BF16>), dim3(8, 2, 32), dim3(256), 0, stream,
                     xbT, (long)MM * NN, wp1T, 0L, pyyT, (long)PP * NN, MM, NN);

  colsum_bf16<<<dim3(64, 32), 256, 0, stream>>>(oyyT, rawO);
  colsum_bf16<<<dim3(64, 32), 256, 0, stream>>>(pyyT, rawP);
  norm_sum<<<32, 256, 0, stream>>>(rawO, g_os, b_os, o_sum);
  norm_sum<<<32, 256, 0, stream>>>(rawP, g_ps, b_ps, p_sum);

  // ---- G3: t2T[b][q][p] (C^T f32) from oyyT @ Wo2 ----
  hipLaunchKernelGGL((gemm_bf16<64, 64, 32, 32, OUT_CT_F32>), dim3(4, 4, 32), dim3(256), 0, stream,
                     oyyT, (long)PP * MM, wo2T, 0L, t2T, (long)PP * PP, MM, PP);
  // ---- G4: p2[b][p][q] (normal f32) from pyyT @ Wp2 ----
  hipLaunchKernelGGL((gemm_bf16<64, 64, 32, 32, OUT_F32>), dim3(4, 4, 32), dim3(256), 0, stream,
                     pyyT, (long)PP * NN, wp2T, 0L, p2, (long)PP * PP, NN, PP);

  stats_part<<<dim3(8, 32), 256, 0, stream>>>(t2T, part);
  stats_fin<<<1, 64, 0, stream>>>(part, stO);
  stats_part<<<dim3(8, 32), 256, 0, stream>>>(p2, part);
  stats_fin<<<1, 64, 0, stream>>>(part, stP);

  prep2<<<8192, 256, 0, stream>>>(t2T, p2, o_sum, p_sum, g_o, b_o, gTp, bTp,
                                  stO, stP, Ap, BpT);

  // ---- G5: proj[b][i][j] = Ap @ BpT^T ----
  hipLaunchKernelGGL((gemm_bf16<64, 64, 32, 32, OUT_F32>), dim3(4, 4, 32), dim3(256), 0, stream,
                     Ap, (long)PP * PP, BpT, (long)PP * PP, proj, (long)PP * PP, PP, PP);

  stats_part<<<dim3(8, 32), 256, 0, stream>>>(proj, part);
  stats_fin<<<1, 64, 0, stream>>>(part, stF);

  final_write<<<8192, 256, 0, stream>>>(proj, stF, g, b_, o_sum, p_sum, out);
}

// Round 3
// 217.114 us; speedup vs baseline: 3.9336x; 1.1120x over previous
//
#include <hip/hip_runtime.h>
#include <hip/hip_bf16.h>

#define PP 256
#define BB 32
#define MM 1024
#define NN 1024

constexpr float EPSF = 1e-5f;

typedef __attribute__((ext_vector_type(8))) short short8v;
typedef __attribute__((ext_vector_type(4))) short short4v;
typedef __attribute__((ext_vector_type(4))) float f32x4;

__device__ inline float bf2f(short s) {
  union { unsigned u; float f; } cv;
  cv.u = ((unsigned)(unsigned short)s) << 16;
  return cv.f;
}
__device__ inline short f2bf(float f) {
  union { float f; unsigned u; } cv; cv.f = f;
  unsigned u = cv.u;
  unsigned r = (u + 0x7fffu + ((u >> 16) & 1u)) >> 16;
  return (short)r;
}

__device__ inline void gload16(const void* g, void* l) {
  __builtin_amdgcn_global_load_lds(
      (const __attribute__((address_space(1))) unsigned*)g,
      (__attribute__((address_space(3))) unsigned*)l, 16, 0, 0);
}

// ---------------------------------------------------------------------------
// 4 weight matrices [1024][256] f32 -> [256][1024] bf16 (transposed), one launch
// ---------------------------------------------------------------------------
__global__ __launch_bounds__(256)
void wconv4(const float* __restrict__ s0, const float* __restrict__ s1,
            const float* __restrict__ s2, const float* __restrict__ s3,
            short* __restrict__ d0, short* __restrict__ d1,
            short* __restrict__ d2, short* __restrict__ d3)
{
  const float* src = (blockIdx.z == 0) ? s0 : (blockIdx.z == 1) ? s1
                    : (blockIdx.z == 2) ? s2 : s3;
  short* dst = (blockIdx.z == 0) ? d0 : (blockIdx.z == 1) ? d1
              : (blockIdx.z == 2) ? d2 : d3;
  __shared__ float tile[64][65];
  const int c0 = blockIdx.x * 64, r0 = blockIdx.y * 64;
  const int tid = threadIdx.x;
#pragma unroll
  for (int i = 0; i < 16; ++i) {
    int idx = i * 256 + tid;
    int r = idx >> 6, c = idx & 63;
    tile[r][c] = src[(long)(r0 + r) * 256 + (c0 + c)];
  }
  __syncthreads();
#pragma unroll
  for (int i = 0; i < 16; ++i) {
    int idx = i * 256 + tid;
    int rr = idx >> 6, cc = idx & 63;
    dst[(long)(c0 + rr) * 1024 + (r0 + cc)] = f2bf(tile[cc][rr]);
  }
}

// g_p,b_p [256][256] f32 -> transposed f32, one launch (z selects)
__global__ __launch_bounds__(256)
void tr2_f32(const float* __restrict__ s0, const float* __restrict__ s1,
             float* __restrict__ d0, float* __restrict__ d1)
{
  const float* src = blockIdx.z ? s1 : s0;
  float* dst = blockIdx.z ? d1 : d0;
  __shared__ float tile[64][65];
  const int c0 = blockIdx.x * 64, r0 = blockIdx.y * 64;
  const int tid = threadIdx.x;
#pragma unroll
  for (int i = 0; i < 16; ++i) {
    int idx = i * 256 + tid;
    int r = idx >> 6, c = idx & 63;
    tile[r][c] = src[(long)(r0 + r) * 256 + (c0 + c)];
  }
  __syncthreads();
#pragma unroll
  for (int i = 0; i < 16; ++i) {
    int idx = i * 256 + tid;
    int rr = idx >> 6, cc = idx & 63;
    dst[(long)(c0 + rr) * 256 + (r0 + cc)] = tile[cc][rr];
  }
}

// ---------------------------------------------------------------------------
// GEMM with f32 A (x, row-major, k-contig) reg-staged->bf16 LDS,
// bf16 BT [256][K] via global_load_lds.  Output: C^T bf16 [256][rows].
// Optionally accumulates rowsum of A (exact f32) from blockIdx.y==0 blocks.
// BM=BN=128, WM=WN=64, BK=32.  A-LDS XOR-swizzled by k-chunk.
// ---------------------------------------------------------------------------
template<bool RSUM>
__global__ __launch_bounds__(256)
void gemm_xf32(const float* __restrict__ A, long aStride,
               const short* __restrict__ BT,
               short* __restrict__ Cout, long cStride,
               float* __restrict__ rowsum,
               int K, int ldc)
{
  constexpr int BM = 128, BN = 128, KC = 4;
  __shared__ short As[KC * BM * 8];
  __shared__ short Bs[KC * BN * 8];

  const int b = blockIdx.z;
  const float* Ab = A + (long)b * aStride;
  const int m0 = blockIdx.x * BM, n0 = blockIdx.y * BN;

  const int tid = threadIdx.x;
  const int l = tid & 63, w = tid >> 6;
  const int wr = w >> 1, wc = w & 1;
  const int lk = l >> 4, lr = l & 15;

  const int sm = tid >> 2, skc = tid & 3;   // A-staging row / k-chunk

  f32x4 acc[4][4];
#pragma unroll
  for (int fm = 0; fm < 4; ++fm)
#pragma unroll
    for (int fn = 0; fn < 4; ++fn)
      acc[fm][fn] = (f32x4){0.f, 0.f, 0.f, 0.f};

  float rs0 = 0.f, rs1 = 0.f;
  const bool doRs = RSUM && (blockIdx.y == 0);

  for (int k0 = 0; k0 < K; k0 += 32) {
    // ---- A: load f32, convert, swizzled ds_write ----
#pragma unroll
    for (int i = 0; i < 2; ++i) {
      const int m = i * 64 + sm;
      const float* src = Ab + (long)(m0 + m) * K + k0 + skc * 8;
      float4 v0 = *reinterpret_cast<const float4*>(src);
      float4 v1 = *reinterpret_cast<const float4*>(src + 4);
      if (doRs) {
        float t = v0.x + v0.y + v0.z + v0.w + v1.x + v1.y + v1.z + v1.w;
        if (i == 0) rs0 += t; else rs1 += t;
      }
      short8v pk;
      pk[0] = f2bf(v0.x); pk[1] = f2bf(v0.y); pk[2] = f2bf(v0.z); pk[3] = f2bf(v0.w);
      pk[4] = f2bf(v1.x); pk[5] = f2bf(v1.y); pk[6] = f2bf(v1.z); pk[7] = f2bf(v1.w);
      const int idx = ((skc * BM + m) * 8) ^ (skc << 4);
      *reinterpret_cast<short8v*>(&As[idx]) = pk;
    }
    // ---- B: global_load_lds bf16 ----
#pragma unroll
    for (int i = 0; i < 2; ++i) {
      const int s = i * 256 + tid;
      const int kc = s >> 7, n = s & 127;
      gload16(BT + (long)(n0 + n) * K + k0 + kc * 8, &Bs[s * 8]);
    }
    __syncthreads();

    short8v af[4], bf[4];
#pragma unroll
    for (int fm = 0; fm < 4; ++fm) {
      const int row = wr * 64 + fm * 16 + lr;
      af[fm] = *reinterpret_cast<const short8v*>(&As[((lk * BM + row) * 8) ^ (lk << 4)]);
    }
#pragma unroll
    for (int fn = 0; fn < 4; ++fn)
      bf[fn] = *reinterpret_cast<const short8v*>(&Bs[(lk * BN + wc * 64 + fn * 16 + lr) * 8]);
#pragma unroll
    for (int fm = 0; fm < 4; ++fm)
#pragma unroll
      for (int fn = 0; fn < 4; ++fn)
        acc[fm][fn] = __builtin_amdgcn_mfma_f32_16x16x32_bf16(
            af[fm], bf[fn], acc[fm][fn], 0, 0, 0);
    __syncthreads();
  }

  if (doRs) {
    rs0 += __shfl_xor(rs0, 1); rs0 += __shfl_xor(rs0, 2);
    rs1 += __shfl_xor(rs1, 1); rs1 += __shfl_xor(rs1, 2);
    if ((tid & 3) == 0) {
      rowsum[(long)b * MM + m0 + sm] = rs0;
      rowsum[(long)b * MM + m0 + 64 + sm] = rs1;
    }
  }

  // C^T bf16: col (p) = n-index, row = m-index
  short* Cb = Cout + (long)b * cStride;
#pragma unroll
  for (int fm = 0; fm < 4; ++fm)
#pragma unroll
    for (int fn = 0; fn < 4; ++fn) {
      const int c = n0 + wc * 64 + fn * 16 + lr;
      const int rb = m0 + wr * 64 + fm * 16 + lk * 4;
      short4v pk;
#pragma unroll
      for (int j = 0; j < 4; ++j) pk[j] = f2bf(acc[fm][fn][j]);
      *reinterpret_cast<short4v*>(&Cb[(long)c * ldc + rb]) = pk;
    }
}

// ---------------------------------------------------------------------------
// bf16 MFMA GEMM (both operands materialized bf16, k-contig).
// ---------------------------------------------------------------------------
enum { OUT_F32 = 0, OUT_CT_F32 = 1 };

template<int BM, int BN, int WM, int WN, int OUTMODE>
__global__ __launch_bounds__(256)
void gemm_bf16(const short* __restrict__ A, long aStride,
               const short* __restrict__ BT, long bStride,
               void* __restrict__ Cout, long cStride,
               int K, int ldc)
{
  constexpr int KC = 4;
  constexpr int WAVES_N = BN / WN;
  constexpr int FM = WM / 16, FN = WN / 16;
  static_assert((BM / WM) * (BN / WN) == 4, "4 waves");
  __shared__ short As[KC * BM * 8];
  __shared__ short Bs[KC * BN * 8];

  const int b = blockIdx.z;
  const short* Ab = A + (long)b * aStride;
  const short* Bb = BT + (long)b * bStride;
  const int m0 = blockIdx.x * BM, n0 = blockIdx.y * BN;

  const int tid = threadIdx.x;
  const int l = tid & 63, w = tid >> 6;
  const int wr = w / WAVES_N, wc = w % WAVES_N;
  const int lk = l >> 4, lr = l & 15;

  f32x4 acc[FM][FN];
#pragma unroll
  for (int fm = 0; fm < FM; ++fm)
#pragma unroll
    for (int fn = 0; fn < FN; ++fn)
      acc[fm][fn] = (f32x4){0.f, 0.f, 0.f, 0.f};

  constexpr int A_IT = (KC * BM) / 256;
  constexpr int B_IT = (KC * BN) / 256;

  for (int k0 = 0; k0 < K; k0 += 32) {
#pragma unroll
    for (int i = 0; i < A_IT; ++i) {
      int s = i * 256 + tid;
      int kc = s / BM, m = s % BM;
      gload16(Ab + (long)(m0 + m) * K + k0 + kc * 8, &As[s * 8]);
    }
#pragma unroll
    for (int i = 0; i < B_IT; ++i) {
      int s = i * 256 + tid;
      int kc = s / BN, n = s % BN;
      gload16(Bb + (long)(n0 + n) * K + k0 + kc * 8, &Bs[s * 8]);
    }
    __syncthreads();

    short8v af[FM], bf[FN];
#pragma unroll
    for (int fm = 0; fm < FM; ++fm)
      af[fm] = *(const short8v*)&As[(lk * BM + wr * WM + fm * 16 + lr) * 8];
#pragma unroll
    for (int fn = 0; fn < FN; ++fn)
      bf[fn] = *(const short8v*)&Bs[(lk * BN + wc * WN + fn * 16 + lr) * 8];
#pragma unroll
    for (int fm = 0; fm < FM; ++fm)
#pragma unroll
      for (int fn = 0; fn < FN; ++fn)
        acc[fm][fn] = __builtin_amdgcn_mfma_f32_16x16x32_bf16(
            af[fm], bf[fn], acc[fm][fn], 0, 0, 0);
    __syncthreads();
  }

  if (OUTMODE == OUT_F32) {
    float* Cb = (float*)Cout + (long)b * cStride;
#pragma unroll
    for (int fm = 0; fm < FM; ++fm)
#pragma unroll
      for (int fn = 0; fn < FN; ++fn) {
        const int c = n0 + wc * WN + fn * 16 + lr;
        const int rb = m0 + wr * WM + fm * 16 + lk * 4;
#pragma unroll
        for (int j = 0; j < 4; ++j)
          Cb[(long)(rb + j) * ldc + c] = acc[fm][fn][j];
      }
  } else {
    float* Cb = (float*)Cout + (long)b * cStride;
#pragma unroll
    for (int fm = 0; fm < FM; ++fm)
#pragma unroll
      for (int fn = 0; fn < FN; ++fn) {
        const int c = n0 + wc * WN + fn * 16 + lr;
        const int rb = m0 + wr * WM + fm * 16 + lk * 4;
        *(f32x4*)&Cb[(long)c * ldc + rb] = acc[fm][fn];
      }
  }
}

// ---------------------------------------------------------------------------
// Row sums of bf16 [B][256][1024] (one wave per row) -> raw[b][256]
// ---------------------------------------------------------------------------
__global__ __launch_bounds__(256)
void colsum_bf16(const short* __restrict__ srcT, float* __restrict__ raw)
{
  const int b = blockIdx.y;
  const int w = threadIdx.x >> 6, l = threadIdx.x & 63;
  const int p = blockIdx.x * 4 + w;
  const short* row = srcT + ((long)b * 256 + p) * 1024;
  short8v v1 = *(const short8v*)&row[l * 8];
  short8v v2 = *(const short8v*)&row[(64 + l) * 8];
  float s = 0.f;
#pragma unroll
  for (int j = 0; j < 8; ++j) s += bf2f(v1[j]) + bf2f(v2[j]);
#pragma unroll
  for (int off = 32; off; off >>= 1) s += __shfl_down(s, off);
  if (l == 0) raw[(long)b * 256 + p] = s;
}

// rawP[b][p] = dot(wp1T[p][:], rowsum_x[b][:])
__global__ __launch_bounds__(256)
void psum_dot(const short* __restrict__ wp1T, const float* __restrict__ rowsum,
              float* __restrict__ rawP)
{
  __shared__ float rsm[1024];
  const int b = blockIdx.x;
  for (int i = threadIdx.x; i < 1024; i += 256) rsm[i] = rowsum[(long)b * 1024 + i];
  __syncthreads();
  const int p = threadIdx.x;
  const short* wrow = wp1T + (long)p * 1024;
  float s = 0.f;
  for (int k = 0; k < 1024; k += 8) {
    short8v v = *(const short8v*)&wrow[k];
#pragma unroll
    for (int j = 0; j < 8; ++j) s = fmaf(bf2f(v[j]), rsm[k + j], s);
  }
  rawP[(long)b * 256 + p] = s;
}

__device__ inline void block_reduce2(float& v1, float& v2, float* red)
{
#pragma unroll
  for (int off = 32; off > 0; off >>= 1) {
    v1 += __shfl_down(v1, off);
    v2 += __shfl_down(v2, off);
  }
  const int lane = threadIdx.x & 63, wid = threadIdx.x >> 6;
  if (lane == 0) { red[wid * 2] = v1; red[wid * 2 + 1] = v2; }
  __syncthreads();
  v1 = red[0] + red[2] + red[4] + red[6];
  v2 = red[1] + red[3] + red[5] + red[7];
}

__global__ __launch_bounds__(256)
void norm_sum(const float* __restrict__ raw, const float* __restrict__ gamma,
              const float* __restrict__ beta, float* __restrict__ out)
{
  const int b = blockIdx.x;
  const int p = threadIdx.x;
  float s = raw[(long)b * 256 + p];
  __shared__ float red[8];
  float v1 = s, v2 = s * s;
  block_reduce2(v1, v2, red);
  const float mean = v1 / 256.0f;
  float var = fmaxf((v2 - v1 * mean) / 255.0f, 0.f);
  const float inv = 1.0f / (sqrtf(var) + EPSF);
  out[(long)b * 256 + p] = gamma[p] * (s - mean) * inv + beta[p] + 1.0f;
}

__global__ __launch_bounds__(256)
void stats_part(const float* __restrict__ src, float* __restrict__ part)
{
  const int b = blockIdx.y, chunk = blockIdx.x;
  const float* s = src + ((long)b << 16) + (long)chunk * 8192;
  float v1 = 0.f, v2 = 0.f;
  for (int i = threadIdx.x; i < 2048; i += 256) {
    float4 x = *reinterpret_cast<const float4*>(&s[i * 4]);
    v1 += x.x + x.y + x.z + x.w;
    v2 = fmaf(x.x, x.x, fmaf(x.y, x.y, fmaf(x.z, x.z, fmaf(x.w, x.w, v2))));
  }
  __shared__ float red[8];
  block_reduce2(v1, v2, red);
  if (threadIdx.x == 0) {
    part[(b * 8 + chunk) * 2] = v1;
    part[(b * 8 + chunk) * 2 + 1] = v2;
  }
}

__global__ void stats_fin(const float* __restrict__ part, float* __restrict__ st)
{
  const int b = threadIdx.x;
  if (b < 32) {
    float v1 = 0.f, v2 = 0.f;
#pragma unroll
    for (int c = 0; c < 8; ++c) {
      v1 += part[(b * 8 + c) * 2];
      v2 += part[(b * 8 + c) * 2 + 1];
    }
    const float mean = v1 / 65536.0f;
    const float var = fmaxf((v2 - v1 * mean) / 65535.0f, 0.f);
    st[b * 2] = mean;
    st[b * 2 + 1] = 1.0f / (sqrtf(var) + EPSF);
  }
}

__global__ __launch_bounds__(256)
void prep2(const float* __restrict__ t2T, const float* __restrict__ p2,
           const float* __restrict__ o_sum, const float* __restrict__ p_sum,
           const float* __restrict__ gamma_o, const float* __restrict__ beta_o,
           const float* __restrict__ gTp, const float* __restrict__ bTp,
           const float* __restrict__ stO, const float* __restrict__ stP,
           short* __restrict__ Ap, short* __restrict__ BpT)
{
  const long idx = (long)blockIdx.x * 256 + threadIdx.x;
  const int b = (int)(idx >> 16);
  const int rc = (int)(idx & 65535);
  const int r = rc >> 8, c = rc & 255;
  const float mO = stO[b * 2], iO = stO[b * 2 + 1];
  const float mP = stP[b * 2], iP = stP[b * 2 + 1];
  const float on = gamma_o[rc] * (t2T[idx] - mO) * iO + beta_o[rc];
  Ap[idx] = f2bf(on * o_sum[(b << 8) + r] * p_sum[(b << 8) + c]);
  const float pn = gTp[rc] * (p2[idx] - mP) * iP + bTp[rc];
  BpT[idx] = f2bf(pn * o_sum[(b << 8) + c] * p_sum[(b << 8) + r]);
}

__global__ __launch_bounds__(256)
void final_write(const float* __restrict__ proj, const float* __restrict__ stF,
                 const float* __restrict__ gamma, const float* __restrict__ beta,
                 const float* __restrict__ o_sum, const float* __restrict__ p_sum,
                 float* __restrict__ out)
{
  const long idx = (long)blockIdx.x * 256 + threadIdx.x;
  const int b = (int)(idx >> 16);
  const int ij = (int)(idx & 65535);
  const int i = ij >> 8, j = ij & 255;
  out[idx] = gamma[ij] * (proj[idx] - stF[b * 2]) * stF[b * 2 + 1] + beta[ij];
  out[(long)BB * 65536 + idx] = o_sum[(b << 8) + i] * p_sum[(b << 8) + j];
}

extern "C" void kernel_launch(void* const* d_in, const int* in_sizes, int n_in,
                              void* d_out, int out_size, void* d_ws, size_t ws_size,
                              hipStream_t stream)
{
  const float* x    = (const float*)d_in[0];
  const float* Wo1  = (const float*)d_in[1];
  const float* Wo2  = (const float*)d_in[2];
  const float* Wp1  = (const float*)d_in[3];
  const float* Wp2  = (const float*)d_in[4];
  const float* g_os = (const float*)d_in[5];
  const float* g_o  = (const float*)d_in[6];
  const float* g_ps = (const float*)d_in[7];
  const float* g_p  = (const float*)d_in[8];
  const float* g    = (const float*)d_in[9];
  const float* b_os = (const float*)d_in[10];
  const float* b_o  = (const float*)d_in[11];
  const float* b_ps = (const float*)d_in[12];
  const float* b_p  = (const float*)d_in[13];
  const float* b_   = (const float*)d_in[14];
  float* out = (float*)d_out;

  // ---- workspace layout ----
  short* wo1T = (short*)d_ws;            // 262144 sh each
  short* wo2T = wo1T + 262144;
  short* wp1T = wo2T + 262144;
  short* wp2T = wp1T + 262144;
  short* oyyT = wp2T + 262144;           // 8,388,608 sh  [B][P][M]
  short* UT   = oyyT + 8388608;          // 8,388,608 sh  [B][P][M]
  float* gTp  = (float*)(UT + 8388608);  // 65536 f
  float* bTp  = gTp + 65536;             // 65536 f
  float* rowsumX = bTp + 65536;          // 32768 f  [B][M]
  float* t2T  = rowsumX + 32768;         // 2,097,152 f  [B][P][P]
  float* p2   = t2T + 2097152;           // 2,097,152 f
  float* proj = p2 + 2097152;            // 2,097,152 f
  short* Ap   = (short*)(proj + 2097152);// 2,097,152 sh
  short* BpT  = Ap + 2097152;            // 2,097,152 sh
  float* rawO = (float*)(BpT + 2097152); // 8192
  float* rawP = rawO + 8192;
  float* o_sum = rawP + 8192;
  float* p_sum = o_sum + 8192;
  float* part  = p_sum + 8192;           // 512
  float* stO   = part + 512;
  float* stP   = stO + 64;
  float* stF   = stP + 64;

  // ---- weight conversions (one launch) + gamma/beta_p transposes ----
  wconv4<<<dim3(4, 16, 4), 256, 0, stream>>>(Wo1, Wo2, Wp1, Wp2,
                                             wo1T, wo2T, wp1T, wp2T);
  tr2_f32<<<dim3(4, 4, 2), 256, 0, stream>>>(g_p, b_p, gTp, bTp);

  // ---- G1: oyyT = (x @ Wo1)^T bf16, + rowsum_x side product ----
  hipLaunchKernelGGL((gemm_xf32<true>), dim3(8, 2, 32), dim3(256), 0, stream,
                     x, (long)MM * NN, wo1T, oyyT, (long)PP * MM, rowsumX, NN, MM);
  // ---- GU: UT = (x @ Wp2)^T bf16 ----
  hipLaunchKernelGGL((gemm_xf32<false>), dim3(8, 2, 32), dim3(256), 0, stream,
                     x, (long)MM * NN, wp2T, UT, (long)PP * MM, nullptr, NN, MM);

  colsum_bf16<<<dim3(64, 32), 256, 0, stream>>>(oyyT, rawO);
  psum_dot<<<32, 256, 0, stream>>>(wp1T, rowsumX, rawP);
  norm_sum<<<32, 256, 0, stream>>>(rawO, g_os, b_os, o_sum);
  norm_sum<<<32, 256, 0, stream>>>(rawP, g_ps, b_ps, p_sum);

  // ---- G3: t2T[b][q][p] = (oyy^T @ Wo2)^T  (C^T f32) ----
  hipLaunchKernelGGL((gemm_bf16<64, 64, 32, 32, OUT_CT_F32>), dim3(4, 4, 32), dim3(256), 0, stream,
                     oyyT, (long)PP * MM, wo2T, 0L, t2T, (long)PP * PP, MM, PP);
  // ---- G4': p2[b][p][q] = Wp1^T @ U = sum_m wp1T[p][m] * UT[q][m] ----
  hipLaunchKernelGGL((gemm_bf16<64, 64, 32, 32, OUT_F32>), dim3(4, 4, 32), dim3(256), 0, stream,
                     wp1T, 0L, UT, (long)PP * MM, p2, (long)PP * PP, MM, PP);

  stats_part<<<dim3(8, 32), 256, 0, stream>>>(t2T, part);
  stats_fin<<<1, 64, 0, stream>>>(part, stO);
  stats_part<<<dim3(8, 32), 256, 0, stream>>>(p2, part);
  stats_fin<<<1, 64, 0, stream>>>(part, stP);

  prep2<<<8192, 256, 0, stream>>>(t2T, p2, o_sum, p_sum, g_o, b_o, gTp, bTp,
                                  stO, stP, Ap, BpT);

  // ---- G5: proj = Ap @ BpT^T ----
  hipLaunchKernelGGL((gemm_bf16<64, 64, 32, 32, OUT_F32>), dim3(4, 4, 32), dim3(256), 0, stream,
                     Ap, (long)PP * PP, BpT, (long)PP * PP, proj, (long)PP * PP, PP, PP);

  stats_part<<<dim3(8, 32), 256, 0, stream>>>(proj, part);
  stats_fin<<<1, 64, 0, stream>>>(part, stF);

  final_write<<<8192, 256, 0, stream>>>(proj, stF, g, b_, o_sum, p_sum, out);
}

// Round 4
// 194.704 us; speedup vs baseline: 4.3864x; 1.1151x over previous
//
#include <hip/hip_runtime.h>
#include <hip/hip_bf16.h>

#define PP 256
#define BB 32
#define MM 1024
#define NN 1024

constexpr float EPSF = 1e-5f;

typedef __attribute__((ext_vector_type(8))) short short8v;
typedef __attribute__((ext_vector_type(4))) short short4v;
typedef __attribute__((ext_vector_type(4))) float f32x4;

__device__ inline float bf2f(short s) {
  union { unsigned u; float f; } cv;
  cv.u = ((unsigned)(unsigned short)s) << 16;
  return cv.f;
}
__device__ inline short f2bf(float f) {
  union { float f; unsigned u; } cv; cv.f = f;
  unsigned u = cv.u;
  unsigned r = (u + 0x7fffu + ((u >> 16) & 1u)) >> 16;
  return (short)r;
}

__device__ inline void gload16(const void* g, void* l) {
  __builtin_amdgcn_global_load_lds(
      (const __attribute__((address_space(1))) unsigned*)g,
      (__attribute__((address_space(3))) unsigned*)l, 16, 0, 0);
}

// ---------------------------------------------------------------------------
// 4 weight matrices [1024][256] f32 -> [256][1024] bf16 (transposed)
// ---------------------------------------------------------------------------
__global__ __launch_bounds__(256)
void wconv4(const float* __restrict__ s0, const float* __restrict__ s1,
            const float* __restrict__ s2, const float* __restrict__ s3,
            short* __restrict__ d0, short* __restrict__ d1,
            short* __restrict__ d2, short* __restrict__ d3)
{
  const float* src = (blockIdx.z == 0) ? s0 : (blockIdx.z == 1) ? s1
                    : (blockIdx.z == 2) ? s2 : s3;
  short* dst = (blockIdx.z == 0) ? d0 : (blockIdx.z == 1) ? d1
              : (blockIdx.z == 2) ? d2 : d3;
  __shared__ float tile[64][65];
  const int c0 = blockIdx.x * 64, r0 = blockIdx.y * 64;
  const int tid = threadIdx.x;
#pragma unroll
  for (int i = 0; i < 16; ++i) {
    int idx = i * 256 + tid;
    int r = idx >> 6, c = idx & 63;
    tile[r][c] = src[(long)(r0 + r) * 256 + (c0 + c)];
  }
  __syncthreads();
#pragma unroll
  for (int i = 0; i < 16; ++i) {
    int idx = i * 256 + tid;
    int rr = idx >> 6, cc = idx & 63;
    dst[(long)(c0 + rr) * 1024 + (r0 + cc)] = f2bf(tile[cc][rr]);
  }
}

__global__ __launch_bounds__(256)
void tr2_f32(const float* __restrict__ s0, const float* __restrict__ s1,
             float* __restrict__ d0, float* __restrict__ d1)
{
  const float* src = blockIdx.z ? s1 : s0;
  float* dst = blockIdx.z ? d1 : d0;
  __shared__ float tile[64][65];
  const int c0 = blockIdx.x * 64, r0 = blockIdx.y * 64;
  const int tid = threadIdx.x;
#pragma unroll
  for (int i = 0; i < 16; ++i) {
    int idx = i * 256 + tid;
    int r = idx >> 6, c = idx & 63;
    tile[r][c] = src[(long)(r0 + r) * 256 + (c0 + c)];
  }
  __syncthreads();
#pragma unroll
  for (int i = 0; i < 16; ++i) {
    int idx = i * 256 + tid;
    int rr = idx >> 6, cc = idx & 63;
    dst[(long)(c0 + rr) * 256 + (r0 + cc)] = tile[cc][rr];
  }
}

// ---------------------------------------------------------------------------
// Merged G1+GU: x (f32 [B][1024][1024]) vs wcat (bf16 [512][1024]).
// n0<256 -> oyyT = (x@Wo1)^T bf16 ; n0>=256 -> UT = (x@Wp2)^T bf16.
// Also emits exact f32 rowsum of x (blocks with blockIdx.y==0).
// BM=BN=128, BK=32, 4 waves of 64x64.  Grid (8,4,32) = 1024 blocks.
// ---------------------------------------------------------------------------
__global__ __launch_bounds__(256)
void gemm_xcat(const float* __restrict__ x, const short* __restrict__ wcat,
               short* __restrict__ oyyT, short* __restrict__ UT,
               float* __restrict__ rowsum)
{
  constexpr int BM = 128, BN = 128;
  __shared__ short As[4 * BM * 8];
  __shared__ short Bs[4 * BN * 8];

  const int b = blockIdx.z;
  const float* Ab = x + (long)b * MM * NN;
  const int m0 = blockIdx.x * BM;
  const int n0 = blockIdx.y * BN;      // 0..511 over wcat rows

  const int tid = threadIdx.x;
  const int l = tid & 63, w = tid >> 6;
  const int wr = w >> 1, wc = w & 1;
  const int lk = l >> 4, lr = l & 15;
  const int sm = tid >> 2, skc = tid & 3;

  f32x4 acc[4][4];
#pragma unroll
  for (int fm = 0; fm < 4; ++fm)
#pragma unroll
    for (int fn = 0; fn < 4; ++fn)
      acc[fm][fn] = (f32x4){0.f, 0.f, 0.f, 0.f};

  float rs0 = 0.f, rs1 = 0.f;
  const bool doRs = (blockIdx.y == 0);

  for (int k0 = 0; k0 < NN; k0 += 32) {
#pragma unroll
    for (int i = 0; i < 2; ++i) {
      const int m = i * 64 + sm;
      const float* src = Ab + (long)(m0 + m) * NN + k0 + skc * 8;
      float4 v0 = *reinterpret_cast<const float4*>(src);
      float4 v1 = *reinterpret_cast<const float4*>(src + 4);
      if (doRs) {
        float t = v0.x + v0.y + v0.z + v0.w + v1.x + v1.y + v1.z + v1.w;
        if (i == 0) rs0 += t; else rs1 += t;
      }
      short8v pk;
      pk[0] = f2bf(v0.x); pk[1] = f2bf(v0.y); pk[2] = f2bf(v0.z); pk[3] = f2bf(v0.w);
      pk[4] = f2bf(v1.x); pk[5] = f2bf(v1.y); pk[6] = f2bf(v1.z); pk[7] = f2bf(v1.w);
      const int idx = ((skc * BM + m) * 8) ^ (skc << 4);
      *reinterpret_cast<short8v*>(&As[idx]) = pk;
    }
#pragma unroll
    for (int i = 0; i < 2; ++i) {
      const int s = i * 256 + tid;
      const int kc = s >> 7, n = s & 127;
      gload16(wcat + (long)(n0 + n) * NN + k0 + kc * 8, &Bs[s * 8]);
    }
    __syncthreads();

    short8v af[4], bf[4];
#pragma unroll
    for (int fm = 0; fm < 4; ++fm) {
      const int row = wr * 64 + fm * 16 + lr;
      af[fm] = *reinterpret_cast<const short8v*>(&As[((lk * BM + row) * 8) ^ (lk << 4)]);
    }
#pragma unroll
    for (int fn = 0; fn < 4; ++fn)
      bf[fn] = *reinterpret_cast<const short8v*>(&Bs[(lk * BN + wc * 64 + fn * 16 + lr) * 8]);
#pragma unroll
    for (int fm = 0; fm < 4; ++fm)
#pragma unroll
      for (int fn = 0; fn < 4; ++fn)
        acc[fm][fn] = __builtin_amdgcn_mfma_f32_16x16x32_bf16(
            af[fm], bf[fn], acc[fm][fn], 0, 0, 0);
    __syncthreads();
  }

  if (doRs) {
    rs0 += __shfl_xor(rs0, 1); rs0 += __shfl_xor(rs0, 2);
    rs1 += __shfl_xor(rs1, 1); rs1 += __shfl_xor(rs1, 2);
    if ((tid & 3) == 0) {
      rowsum[(long)b * MM + m0 + sm] = rs0;
      rowsum[(long)b * MM + m0 + 64 + sm] = rs1;
    }
  }

  short* Cb = ((n0 < 256) ? oyyT : UT) + (long)b * PP * MM;
  const int nb = n0 & 255;
#pragma unroll
  for (int fm = 0; fm < 4; ++fm)
#pragma unroll
    for (int fn = 0; fn < 4; ++fn) {
      const int c = nb + wc * 64 + fn * 16 + lr;
      const int rb = m0 + wr * 64 + fm * 16 + lk * 4;
      short4v pk;
#pragma unroll
      for (int j = 0; j < 4; ++j) pk[j] = f2bf(acc[fm][fn][j]);
      *reinterpret_cast<short4v*>(&Cb[(long)c * MM + rb]) = pk;
    }
}

// ---------------------------------------------------------------------------
// Merged G3+G4': 64x64 tiles, K=1024, C^T f32 epilogue.
//  z<32 : t2T[z][q][p] from A=oyyT[z], BT=wo2T
//  z>=32: p2[z-32][p][q] from A=UT[z-32], BT=wp1T   (operand swap -> row-major)
// ---------------------------------------------------------------------------
__global__ __launch_bounds__(256)
void gemm_dual(const short* __restrict__ oyyT, const short* __restrict__ wo2T,
               const short* __restrict__ UT, const short* __restrict__ wp1T,
               float* __restrict__ t2T, float* __restrict__ p2)
{
  constexpr int BM = 64, BN = 64;
  __shared__ short As[4 * BM * 8];
  __shared__ short Bs[4 * BN * 8];

  const int z = blockIdx.z;
  const short* Ab; const short* Bb; float* Cb;
  if (z < 32) { Ab = oyyT + (long)z * PP * MM; Bb = wo2T; Cb = t2T + ((long)z << 16); }
  else { Ab = UT + (long)(z - 32) * PP * MM; Bb = wp1T; Cb = p2 + ((long)(z - 32) << 16); }

  const int m0 = blockIdx.x * BM, n0 = blockIdx.y * BN;
  const int tid = threadIdx.x;
  const int l = tid & 63, w = tid >> 6;
  const int wr = w >> 1, wc = w & 1;
  const int lk = l >> 4, lr = l & 15;

  f32x4 acc[2][2];
#pragma unroll
  for (int fm = 0; fm < 2; ++fm)
#pragma unroll
    for (int fn = 0; fn < 2; ++fn)
      acc[fm][fn] = (f32x4){0.f, 0.f, 0.f, 0.f};

  for (int k0 = 0; k0 < MM; k0 += 32) {
    {
      const int kc = tid >> 6, m = tid & 63;
      gload16(Ab + (long)(m0 + m) * MM + k0 + kc * 8, &As[tid * 8]);
      gload16(Bb + (long)(n0 + m) * MM + k0 + kc * 8, &Bs[tid * 8]);
    }
    __syncthreads();
    short8v af[2], bf[2];
#pragma unroll
    for (int fm = 0; fm < 2; ++fm)
      af[fm] = *(const short8v*)&As[(lk * BM + wr * 32 + fm * 16 + lr) * 8];
#pragma unroll
    for (int fn = 0; fn < 2; ++fn)
      bf[fn] = *(const short8v*)&Bs[(lk * BN + wc * 32 + fn * 16 + lr) * 8];
#pragma unroll
    for (int fm = 0; fm < 2; ++fm)
#pragma unroll
      for (int fn = 0; fn < 2; ++fn)
        acc[fm][fn] = __builtin_amdgcn_mfma_f32_16x16x32_bf16(
            af[fm], bf[fn], acc[fm][fn], 0, 0, 0);
    __syncthreads();
  }

#pragma unroll
  for (int fm = 0; fm < 2; ++fm)
#pragma unroll
    for (int fn = 0; fn < 2; ++fn) {
      const int c = n0 + wc * 32 + fn * 16 + lr;
      const int rb = m0 + wr * 32 + fm * 16 + lk * 4;
      *(f32x4*)&Cb[(long)c * PP + rb] = acc[fm][fn];
    }
}

// ---------------------------------------------------------------------------
// G5: proj[b][i][j] = Ap @ BpT^T  (row-major f32 out)
// ---------------------------------------------------------------------------
__global__ __launch_bounds__(256)
void gemm_pp(const short* __restrict__ A, const short* __restrict__ BT,
             float* __restrict__ C)
{
  constexpr int BM = 64, BN = 64;
  __shared__ short As[4 * BM * 8];
  __shared__ short Bs[4 * BN * 8];
  const int b = blockIdx.z;
  const short* Ab = A + ((long)b << 16);
  const short* Bb = BT + ((long)b << 16);
  float* Cb = C + ((long)b << 16);
  const int m0 = blockIdx.x * BM, n0 = blockIdx.y * BN;
  const int tid = threadIdx.x;
  const int l = tid & 63, w = tid >> 6;
  const int wr = w >> 1, wc = w & 1;
  const int lk = l >> 4, lr = l & 15;

  f32x4 acc[2][2];
#pragma unroll
  for (int fm = 0; fm < 2; ++fm)
#pragma unroll
    for (int fn = 0; fn < 2; ++fn)
      acc[fm][fn] = (f32x4){0.f, 0.f, 0.f, 0.f};

  for (int k0 = 0; k0 < PP; k0 += 32) {
    {
      const int kc = tid >> 6, m = tid & 63;
      gload16(Ab + (long)(m0 + m) * PP + k0 + kc * 8, &As[tid * 8]);
      gload16(Bb + (long)(n0 + m) * PP + k0 + kc * 8, &Bs[tid * 8]);
    }
    __syncthreads();
    short8v af[2], bf[2];
#pragma unroll
    for (int fm = 0; fm < 2; ++fm)
      af[fm] = *(const short8v*)&As[(lk * BM + wr * 32 + fm * 16 + lr) * 8];
#pragma unroll
    for (int fn = 0; fn < 2; ++fn)
      bf[fn] = *(const short8v*)&Bs[(lk * BN + wc * 32 + fn * 16 + lr) * 8];
#pragma unroll
    for (int fm = 0; fm < 2; ++fm)
#pragma unroll
      for (int fn = 0; fn < 2; ++fn)
        acc[fm][fn] = __builtin_amdgcn_mfma_f32_16x16x32_bf16(
            af[fm], bf[fn], acc[fm][fn], 0, 0, 0);
    __syncthreads();
  }

#pragma unroll
  for (int fm = 0; fm < 2; ++fm)
#pragma unroll
    for (int fn = 0; fn < 2; ++fn) {
      const int c = n0 + wc * 32 + fn * 16 + lr;
      const int rb = m0 + wr * 32 + fm * 16 + lk * 4;
#pragma unroll
      for (int j = 0; j < 4; ++j)
        Cb[(long)(rb + j) * PP + c] = acc[fm][fn][j];
    }
}

// ---------------------------------------------------------------------------
__global__ __launch_bounds__(256)
void colsum_bf16(const short* __restrict__ srcT, float* __restrict__ raw)
{
  const int b = blockIdx.y;
  const int w = threadIdx.x >> 6, l = threadIdx.x & 63;
  const int p = blockIdx.x * 4 + w;
  const short* row = srcT + ((long)b * 256 + p) * 1024;
  short8v v1 = *(const short8v*)&row[l * 8];
  short8v v2 = *(const short8v*)&row[(64 + l) * 8];
  float s = 0.f;
#pragma unroll
  for (int j = 0; j < 8; ++j) s += bf2f(v1[j]) + bf2f(v2[j]);
#pragma unroll
  for (int off = 32; off; off >>= 1) s += __shfl_down(s, off);
  if (l == 0) raw[(long)b * 256 + p] = s;
}

__global__ __launch_bounds__(256)
void psum_dot(const short* __restrict__ wp1T, const float* __restrict__ rowsum,
              float* __restrict__ rawP)
{
  __shared__ float rsm[1024];
  const int b = blockIdx.x;
  for (int i = threadIdx.x; i < 1024; i += 256) rsm[i] = rowsum[(long)b * 1024 + i];
  __syncthreads();
  const int p = threadIdx.x;
  const short* wrow = wp1T + (long)p * 1024;
  float s = 0.f;
  for (int k = 0; k < 1024; k += 8) {
    short8v v = *(const short8v*)&wrow[k];
#pragma unroll
    for (int j = 0; j < 8; ++j) s = fmaf(bf2f(v[j]), rsm[k + j], s);
  }
  rawP[(long)b * 256 + p] = s;
}

__device__ inline void block_reduce2(float& v1, float& v2, float* red)
{
#pragma unroll
  for (int off = 32; off > 0; off >>= 1) {
    v1 += __shfl_down(v1, off);
    v2 += __shfl_down(v2, off);
  }
  const int lane = threadIdx.x & 63, wid = threadIdx.x >> 6;
  if (lane == 0) { red[wid * 2] = v1; red[wid * 2 + 1] = v2; }
  __syncthreads();
  v1 = red[0] + red[2] + red[4] + red[6];
  v2 = red[1] + red[3] + red[5] + red[7];
}

// both sum-normalizations in one launch: blockIdx.x<32 -> o, else p
__global__ __launch_bounds__(256)
void norm_sum2(const float* __restrict__ raw2,
               const float* __restrict__ g_os, const float* __restrict__ b_os,
               const float* __restrict__ g_ps, const float* __restrict__ b_ps,
               float* __restrict__ o_sum, float* __restrict__ p_sum)
{
  const int bb = blockIdx.x;
  const bool isP = bb >= 32;
  const int b = bb & 31;
  const float* raw = raw2 + (isP ? 8192 : 0);
  const float* gamma = isP ? g_ps : g_os;
  const float* beta = isP ? b_ps : b_os;
  float* outp = isP ? p_sum : o_sum;
  const int p = threadIdx.x;
  float s = raw[(long)b * 256 + p];
  __shared__ float red[8];
  float v1 = s, v2 = s * s;
  block_reduce2(v1, v2, red);
  const float mean = v1 / 256.0f;
  float var = fmaxf((v2 - v1 * mean) / 255.0f, 0.f);
  const float inv = 1.0f / (sqrtf(var) + EPSF);
  outp[(long)b * 256 + p] = gamma[p] * (s - mean) * inv + beta[p] + 1.0f;
}

// stats partials for t2T (y<32) and p2 (y>=32): part[y][chunk][2]
__global__ __launch_bounds__(256)
void stats_dual(const float* __restrict__ t2T, const float* __restrict__ p2,
                float* __restrict__ part)
{
  const int y = blockIdx.y, chunk = blockIdx.x;
  const float* s = (y < 32 ? t2T + ((long)y << 16)
                           : p2 + ((long)(y - 32) << 16)) + (long)chunk * 8192;
  float v1 = 0.f, v2 = 0.f;
  for (int i = threadIdx.x; i < 2048; i += 256) {
    float4 xv = *reinterpret_cast<const float4*>(&s[i * 4]);
    v1 += xv.x + xv.y + xv.z + xv.w;
    v2 = fmaf(xv.x, xv.x, fmaf(xv.y, xv.y, fmaf(xv.z, xv.z, fmaf(xv.w, xv.w, v2))));
  }
  __shared__ float red[8];
  block_reduce2(v1, v2, red);
  if (threadIdx.x == 0) {
    part[(y * 8 + chunk) * 2] = v1;
    part[(y * 8 + chunk) * 2 + 1] = v2;
  }
}

__global__ void stats_fin2(const float* __restrict__ part,
                           float* __restrict__ stO, float* __restrict__ stP)
{
  const int t = threadIdx.x;   // 64
  const int y = t;
  float v1 = 0.f, v2 = 0.f;
#pragma unroll
  for (int c = 0; c < 8; ++c) {
    v1 += part[(y * 8 + c) * 2];
    v2 += part[(y * 8 + c) * 2 + 1];
  }
  const float mean = v1 / 65536.0f;
  const float var = fmaxf((v2 - v1 * mean) / 65535.0f, 0.f);
  float* st = (t < 32) ? stO : stP;
  st[(t & 31) * 2] = mean;
  st[(t & 31) * 2 + 1] = 1.0f / (sqrtf(var) + EPSF);
}

__global__ __launch_bounds__(256)
void stats_part(const float* __restrict__ src, float* __restrict__ part)
{
  const int b = blockIdx.y, chunk = blockIdx.x;
  const float* s = src + ((long)b << 16) + (long)chunk * 8192;
  float v1 = 0.f, v2 = 0.f;
  for (int i = threadIdx.x; i < 2048; i += 256) {
    float4 xv = *reinterpret_cast<const float4*>(&s[i * 4]);
    v1 += xv.x + xv.y + xv.z + xv.w;
    v2 = fmaf(xv.x, xv.x, fmaf(xv.y, xv.y, fmaf(xv.z, xv.z, fmaf(xv.w, xv.w, v2))));
  }
  __shared__ float red[8];
  block_reduce2(v1, v2, red);
  if (threadIdx.x == 0) {
    part[(b * 8 + chunk) * 2] = v1;
    part[(b * 8 + chunk) * 2 + 1] = v2;
  }
}

__global__ void stats_fin(const float* __restrict__ part, float* __restrict__ st)
{
  const int b = threadIdx.x;
  if (b < 32) {
    float v1 = 0.f, v2 = 0.f;
#pragma unroll
    for (int c = 0; c < 8; ++c) {
      v1 += part[(b * 8 + c) * 2];
      v2 += part[(b * 8 + c) * 2 + 1];
    }
    const float mean = v1 / 65536.0f;
    const float var = fmaxf((v2 - v1 * mean) / 65535.0f, 0.f);
    st[b * 2] = mean;
    st[b * 2 + 1] = 1.0f / (sqrtf(var) + EPSF);
  }
}

// builds Ap/BpT bf16 and writes the relations output half
__global__ __launch_bounds__(256)
void prep2(const float* __restrict__ t2T, const float* __restrict__ p2,
           const float* __restrict__ o_sum, const float* __restrict__ p_sum,
           const float* __restrict__ gamma_o, const float* __restrict__ beta_o,
           const float* __restrict__ gTp, const float* __restrict__ bTp,
           const float* __restrict__ stO, const float* __restrict__ stP,
           short* __restrict__ Ap, short* __restrict__ BpT,
           float* __restrict__ out)
{
  const long idx = (long)blockIdx.x * 256 + threadIdx.x;
  const int b = (int)(idx >> 16);
  const int rc = (int)(idx & 65535);
  const int r = rc >> 8, c = rc & 255;
  const float mO = stO[b * 2], iO = stO[b * 2 + 1];
  const float mP = stP[b * 2], iP = stP[b * 2 + 1];
  const float relA = o_sum[(b << 8) + r] * p_sum[(b << 8) + c];
  const float on = gamma_o[rc] * (t2T[idx] - mO) * iO + beta_o[rc];
  Ap[idx] = f2bf(on * relA);
  const float pn = gTp[rc] * (p2[idx] - mP) * iP + bTp[rc];
  BpT[idx] = f2bf(pn * o_sum[(b << 8) + c] * p_sum[(b << 8) + r]);
  out[(long)BB * 65536 + idx] = relA;
}

__global__ __launch_bounds__(256)
void final_half(const float* __restrict__ proj, const float* __restrict__ stF,
                const float* __restrict__ gamma, const float* __restrict__ beta,
                float* __restrict__ out)
{
  const long idx = (long)blockIdx.x * 256 + threadIdx.x;
  const int b = (int)(idx >> 16);
  const int ij = (int)(idx & 65535);
  out[idx] = gamma[ij] * (proj[idx] - stF[b * 2]) * stF[b * 2 + 1] + beta[ij];
}

extern "C" void kernel_launch(void* const* d_in, const int* in_sizes, int n_in,
                              void* d_out, int out_size, void* d_ws, size_t ws_size,
                              hipStream_t stream)
{
  const float* x    = (const float*)d_in[0];
  const float* Wo1  = (const float*)d_in[1];
  const float* Wo2  = (const float*)d_in[2];
  const float* Wp1  = (const float*)d_in[3];
  const float* Wp2  = (const float*)d_in[4];
  const float* g_os = (const float*)d_in[5];
  const float* g_o  = (const float*)d_in[6];
  const float* g_ps = (const float*)d_in[7];
  const float* g_p  = (const float*)d_in[8];
  const float* g    = (const float*)d_in[9];
  const float* b_os = (const float*)d_in[10];
  const float* b_o  = (const float*)d_in[11];
  const float* b_ps = (const float*)d_in[12];
  const float* b_p  = (const float*)d_in[13];
  const float* b_   = (const float*)d_in[14];
  float* out = (float*)d_out;

  // ---- workspace ----
  short* wcat = (short*)d_ws;            // [512][1024] = wo1T ; wp2T
  short* wo2T = wcat + 524288;
  short* wp1T = wo2T + 262144;
  short* oyyT = wp1T + 262144;           // [B][256][1024]
  short* UT   = oyyT + 8388608;          // [B][256][1024]
  float* gTp  = (float*)(UT + 8388608);
  float* bTp  = gTp + 65536;
  float* rowsumX = bTp + 65536;          // [B][1024]
  float* t2T  = rowsumX + 32768;         // [B][256][256]
  float* p2   = t2T + 2097152;
  float* proj = p2 + 2097152;
  short* Ap   = (short*)(proj + 2097152);
  short* BpT  = Ap + 2097152;
  float* raw2 = (float*)(BpT + 2097152); // [2][32][256]
  float* o_sum = raw2 + 16384;
  float* p_sum = o_sum + 8192;
  float* part  = p_sum + 8192;           // [64][8][2]
  float* partF = part + 1024;            // [32][8][2]
  float* stO   = partF + 512;
  float* stP   = stO + 64;
  float* stF   = stP + 64;

  wconv4<<<dim3(4, 16, 4), 256, 0, stream>>>(Wo1, Wo2, Wp1, Wp2,
                                             wcat, wo2T, wp1T, wcat + 262144);
  tr2_f32<<<dim3(4, 4, 2), 256, 0, stream>>>(g_p, b_p, gTp, bTp);

  gemm_xcat<<<dim3(8, 4, 32), 256, 0, stream>>>(x, wcat, oyyT, UT, rowsumX);

  colsum_bf16<<<dim3(64, 32), 256, 0, stream>>>(oyyT, raw2);
  psum_dot<<<32, 256, 0, stream>>>(wp1T, rowsumX, raw2 + 8192);
  norm_sum2<<<64, 256, 0, stream>>>(raw2, g_os, b_os, g_ps, b_ps, o_sum, p_sum);

  gemm_dual<<<dim3(4, 4, 64), 256, 0, stream>>>(oyyT, wo2T, UT, wp1T, t2T, p2);

  stats_dual<<<dim3(8, 64), 256, 0, stream>>>(t2T, p2, part);
  stats_fin2<<<1, 64, 0, stream>>>(part, stO, stP);

  prep2<<<8192, 256, 0, stream>>>(t2T, p2, o_sum, p_sum, g_o, b_o, gTp, bTp,
                                  stO, stP, Ap, BpT, out);

  gemm_pp<<<dim3(4, 4, 32), 256, 0, stream>>>(Ap, BpT, proj);

  stats_part<<<dim3(8, 32), 256, 0, stream>>>(proj, partF);
  stats_fin<<<1, 64, 0, stream>>>(partF, stF);

  final_half<<<8192, 256, 0, stream>>>(proj, stF, g, b_, out);
}

// Round 5
// 168.942 us; speedup vs baseline: 5.0552x; 1.1525x over previous
//
#include <hip/hip_runtime.h>
#include <hip/hip_bf16.h>

#define PP 256
#define BB 32
#define MM 1024
#define NN 1024

constexpr float EPSF = 1e-5f;

typedef __attribute__((ext_vector_type(8))) short short8v;
typedef __attribute__((ext_vector_type(4))) short short4v;
typedef __attribute__((ext_vector_type(4))) float f32x4;

__device__ inline float bf2f(short s) {
  union { unsigned u; float f; } cv;
  cv.u = ((unsigned)(unsigned short)s) << 16;
  return cv.f;
}
__device__ inline short f2bf(float f) {
  union { float f; unsigned u; } cv; cv.f = f;
  unsigned u = cv.u;
  unsigned r = (u + 0x7fffu + ((u >> 16) & 1u)) >> 16;
  return (short)r;
}

__device__ inline void gload16(const void* g, void* l) {
  __builtin_amdgcn_global_load_lds(
      (const __attribute__((address_space(1))) unsigned*)g,
      (__attribute__((address_space(3))) unsigned*)l, 16, 0, 0);
}

// ---------------------------------------------------------------------------
// 4 weight matrices [1024][256] f32 -> [256][1024] bf16 (transposed)
// ---------------------------------------------------------------------------
__global__ __launch_bounds__(256)
void wconv4(const float* __restrict__ s0, const float* __restrict__ s1,
            const float* __restrict__ s2, const float* __restrict__ s3,
            short* __restrict__ d0, short* __restrict__ d1,
            short* __restrict__ d2, short* __restrict__ d3)
{
  const float* src = (blockIdx.z == 0) ? s0 : (blockIdx.z == 1) ? s1
                    : (blockIdx.z == 2) ? s2 : s3;
  short* dst = (blockIdx.z == 0) ? d0 : (blockIdx.z == 1) ? d1
              : (blockIdx.z == 2) ? d2 : d3;
  __shared__ float tile[64][65];
  const int c0 = blockIdx.x * 64, r0 = blockIdx.y * 64;
  const int tid = threadIdx.x;
#pragma unroll
  for (int i = 0; i < 16; ++i) {
    int idx = i * 256 + tid;
    int r = idx >> 6, c = idx & 63;
    tile[r][c] = src[(long)(r0 + r) * 256 + (c0 + c)];
  }
  __syncthreads();
#pragma unroll
  for (int i = 0; i < 16; ++i) {
    int idx = i * 256 + tid;
    int rr = idx >> 6, cc = idx & 63;
    dst[(long)(c0 + rr) * 1024 + (r0 + cc)] = f2bf(tile[cc][rr]);
  }
}

__global__ __launch_bounds__(256)
void tr2_f32(const float* __restrict__ s0, const float* __restrict__ s1,
             float* __restrict__ d0, float* __restrict__ d1)
{
  const float* src = blockIdx.z ? s1 : s0;
  float* dst = blockIdx.z ? d1 : d0;
  __shared__ float tile[64][65];
  const int c0 = blockIdx.x * 64, r0 = blockIdx.y * 64;
  const int tid = threadIdx.x;
#pragma unroll
  for (int i = 0; i < 16; ++i) {
    int idx = i * 256 + tid;
    int r = idx >> 6, c = idx & 63;
    tile[r][c] = src[(long)(r0 + r) * 256 + (c0 + c)];
  }
  __syncthreads();
#pragma unroll
  for (int i = 0; i < 16; ++i) {
    int idx = i * 256 + tid;
    int rr = idx >> 6, cc = idx & 63;
    dst[(long)(c0 + rr) * 256 + (r0 + cc)] = tile[cc][rr];
  }
}

// ---------------------------------------------------------------------------
// Merged G1+GU, 2-phase pipelined.
// x f32 [B][1024][1024] vs wcat bf16 [512][1024].
// n0<256 -> oyyT bf16 C^T; else UT.  Rowsum of x from blockIdx.y==0.
// BM=BN=128, BK=32, double-buffered LDS, 1 barrier per K-step.
// ---------------------------------------------------------------------------
__global__ __launch_bounds__(256, 4)
void gemm_xcat(const float* __restrict__ x, const short* __restrict__ wcat,
               short* __restrict__ oyyT, short* __restrict__ UT,
               float* __restrict__ rowsum)
{
  constexpr int BM = 128, BN = 128;
  __shared__ short As[2][4 * BM * 8];
  __shared__ short Bs[2][4 * BN * 8];

  const int b = blockIdx.z;
  const float* Ab = x + (long)b * MM * NN;
  const int m0 = blockIdx.x * BM;
  const int n0 = blockIdx.y * BN;

  const int tid = threadIdx.x;
  const int l = tid & 63, w = tid >> 6;
  const int wr = w >> 1, wc = w & 1;
  const int lk = l >> 4, lr = l & 15;
  const int sm = tid >> 2, skc = tid & 3;

  const float* aptr0 = Ab + (long)(m0 + sm) * NN + skc * 8;
  const float* aptr1 = Ab + (long)(m0 + 64 + sm) * NN + skc * 8;
  const int bn = tid & 127, bk0 = (tid >> 7) * 8;
  const short* bptr = wcat + (long)(n0 + bn) * NN + bk0;

  const int sA0 = ((skc * BM + sm) * 8) ^ (skc << 4);
  const int sA1 = ((skc * BM + 64 + sm) * 8) ^ (skc << 4);

  f32x4 acc[4][4];
#pragma unroll
  for (int fm = 0; fm < 4; ++fm)
#pragma unroll
    for (int fn = 0; fn < 4; ++fn)
      acc[fm][fn] = (f32x4){0.f, 0.f, 0.f, 0.f};

  float rs0 = 0.f, rs1 = 0.f;
  const bool doRs = (blockIdx.y == 0);
  float4 a00, a01, a10, a11;

#define XCAT_LOAD_A(k0_) do { \
    a00 = *reinterpret_cast<const float4*>(aptr0 + (k0_)); \
    a01 = *reinterpret_cast<const float4*>(aptr0 + (k0_) + 4); \
    a10 = *reinterpret_cast<const float4*>(aptr1 + (k0_)); \
    a11 = *reinterpret_cast<const float4*>(aptr1 + (k0_) + 4); \
  } while (0)

#define XCAT_STAGE_B(buf_, k0_) do { \
    gload16(bptr + (k0_), &Bs[buf_][tid * 8]); \
    gload16(bptr + (k0_) + 16, &Bs[buf_][(tid + 256) * 8]); \
  } while (0)

#define XCAT_STAGE_A(buf_) do { \
    if (doRs) { \
      rs0 += a00.x + a00.y + a00.z + a00.w + a01.x + a01.y + a01.z + a01.w; \
      rs1 += a10.x + a10.y + a10.z + a10.w + a11.x + a11.y + a11.z + a11.w; \
    } \
    short8v pk0, pk1; \
    pk0[0] = f2bf(a00.x); pk0[1] = f2bf(a00.y); pk0[2] = f2bf(a00.z); pk0[3] = f2bf(a00.w); \
    pk0[4] = f2bf(a01.x); pk0[5] = f2bf(a01.y); pk0[6] = f2bf(a01.z); pk0[7] = f2bf(a01.w); \
    pk1[0] = f2bf(a10.x); pk1[1] = f2bf(a10.y); pk1[2] = f2bf(a10.z); pk1[3] = f2bf(a10.w); \
    pk1[4] = f2bf(a11.x); pk1[5] = f2bf(a11.y); pk1[6] = f2bf(a11.z); pk1[7] = f2bf(a11.w); \
    *reinterpret_cast<short8v*>(&As[buf_][sA0]) = pk0; \
    *reinterpret_cast<short8v*>(&As[buf_][sA1]) = pk1; \
  } while (0)

  // prologue: tile 0
  XCAT_LOAD_A(0);
  XCAT_STAGE_B(0, 0);
  XCAT_STAGE_A(0);
  __syncthreads();

  for (int kt = 0; kt < 32; ++kt) {
    const int cur = kt & 1, nxt = cur ^ 1;
    if (kt < 31) {
      const int k1 = (kt + 1) * 32;
      XCAT_LOAD_A(k1);
      XCAT_STAGE_B(nxt, k1);
    }
    short8v af[4], bf[4];
#pragma unroll
    for (int fm = 0; fm < 4; ++fm) {
      const int row = wr * 64 + fm * 16 + lr;
      af[fm] = *reinterpret_cast<const short8v*>(&As[cur][((lk * BM + row) * 8) ^ (lk << 4)]);
    }
#pragma unroll
    for (int fn = 0; fn < 4; ++fn)
      bf[fn] = *reinterpret_cast<const short8v*>(&Bs[cur][(lk * BN + wc * 64 + fn * 16 + lr) * 8]);
#pragma unroll
    for (int fm = 0; fm < 4; ++fm)
#pragma unroll
      for (int fn = 0; fn < 4; ++fn)
        acc[fm][fn] = __builtin_amdgcn_mfma_f32_16x16x32_bf16(
            af[fm], bf[fn], acc[fm][fn], 0, 0, 0);
    if (kt < 31) XCAT_STAGE_A(nxt);
    __syncthreads();
  }

  if (doRs) {
    rs0 += __shfl_xor(rs0, 1); rs0 += __shfl_xor(rs0, 2);
    rs1 += __shfl_xor(rs1, 1); rs1 += __shfl_xor(rs1, 2);
    if ((tid & 3) == 0) {
      rowsum[(long)b * MM + m0 + sm] = rs0;
      rowsum[(long)b * MM + m0 + 64 + sm] = rs1;
    }
  }

  short* Cb = ((n0 < 256) ? oyyT : UT) + (long)b * PP * MM;
  const int nb = n0 & 255;
#pragma unroll
  for (int fm = 0; fm < 4; ++fm)
#pragma unroll
    for (int fn = 0; fn < 4; ++fn) {
      const int c = nb + wc * 64 + fn * 16 + lr;
      const int rb = m0 + wr * 64 + fm * 16 + lk * 4;
      short4v pk;
#pragma unroll
      for (int j = 0; j < 4; ++j) pk[j] = f2bf(acc[fm][fn][j]);
      *reinterpret_cast<short4v*>(&Cb[(long)c * MM + rb]) = pk;
    }
}

// ---------------------------------------------------------------------------
// Merged G3+G4', 2-phase pipelined.  64x64 tiles, K=1024, C^T f32 out.
// ---------------------------------------------------------------------------
__global__ __launch_bounds__(256)
void gemm_dual(const short* __restrict__ oyyT, const short* __restrict__ wo2T,
               const short* __restrict__ UT, const short* __restrict__ wp1T,
               float* __restrict__ t2T, float* __restrict__ p2)
{
  constexpr int BM = 64, BN = 64;
  __shared__ short As[2][4 * BM * 8];
  __shared__ short Bs[2][4 * BN * 8];

  const int z = blockIdx.z;
  const short* Ab; const short* Bb; float* Cb;
  if (z < 32) { Ab = oyyT + (long)z * PP * MM; Bb = wo2T; Cb = t2T + ((long)z << 16); }
  else { Ab = UT + (long)(z - 32) * PP * MM; Bb = wp1T; Cb = p2 + ((long)(z - 32) << 16); }

  const int m0 = blockIdx.x * BM, n0 = blockIdx.y * BN;
  const int tid = threadIdx.x;
  const int l = tid & 63, w = tid >> 6;
  const int wr = w >> 1, wc = w & 1;
  const int lk = l >> 4, lr = l & 15;
  const int kc = tid >> 6, mloc = tid & 63;
  const short* aP = Ab + (long)(m0 + mloc) * MM + kc * 8;
  const short* bP = Bb + (long)(n0 + mloc) * MM + kc * 8;

  f32x4 acc[2][2];
#pragma unroll
  for (int fm = 0; fm < 2; ++fm)
#pragma unroll
    for (int fn = 0; fn < 2; ++fn)
      acc[fm][fn] = (f32x4){0.f, 0.f, 0.f, 0.f};

  gload16(aP, &As[0][tid * 8]);
  gload16(bP, &Bs[0][tid * 8]);
  __syncthreads();

  for (int kt = 0; kt < 32; ++kt) {
    const int cur = kt & 1, nxt = cur ^ 1;
    if (kt < 31) {
      gload16(aP + (kt + 1) * 32, &As[nxt][tid * 8]);
      gload16(bP + (kt + 1) * 32, &Bs[nxt][tid * 8]);
    }
    short8v af[2], bf[2];
#pragma unroll
    for (int fm = 0; fm < 2; ++fm)
      af[fm] = *(const short8v*)&As[cur][(lk * BM + wr * 32 + fm * 16 + lr) * 8];
#pragma unroll
    for (int fn = 0; fn < 2; ++fn)
      bf[fn] = *(const short8v*)&Bs[cur][(lk * BN + wc * 32 + fn * 16 + lr) * 8];
#pragma unroll
    for (int fm = 0; fm < 2; ++fm)
#pragma unroll
      for (int fn = 0; fn < 2; ++fn)
        acc[fm][fn] = __builtin_amdgcn_mfma_f32_16x16x32_bf16(
            af[fm], bf[fn], acc[fm][fn], 0, 0, 0);
    __syncthreads();
  }

#pragma unroll
  for (int fm = 0; fm < 2; ++fm)
#pragma unroll
    for (int fn = 0; fn < 2; ++fn) {
      const int c = n0 + wc * 32 + fn * 16 + lr;
      const int rb = m0 + wr * 32 + fm * 16 + lk * 4;
      *(f32x4*)&Cb[(long)c * PP + rb] = acc[fm][fn];
    }
}

// ---------------------------------------------------------------------------
// G5: proj = Ap @ BpT^T (row-major f32 out), 2-phase pipelined, K=256.
// ---------------------------------------------------------------------------
__global__ __launch_bounds__(256)
void gemm_pp(const short* __restrict__ A, const short* __restrict__ BT,
             float* __restrict__ C)
{
  constexpr int BM = 64, BN = 64;
  __shared__ short As[2][4 * BM * 8];
  __shared__ short Bs[2][4 * BN * 8];
  const int b = blockIdx.z;
  const short* Ab = A + ((long)b << 16);
  const short* Bb = BT + ((long)b << 16);
  float* Cb = C + ((long)b << 16);
  const int m0 = blockIdx.x * BM, n0 = blockIdx.y * BN;
  const int tid = threadIdx.x;
  const int l = tid & 63, w = tid >> 6;
  const int wr = w >> 1, wc = w & 1;
  const int lk = l >> 4, lr = l & 15;
  const int kc = tid >> 6, mloc = tid & 63;
  const short* aP = Ab + (long)(m0 + mloc) * PP + kc * 8;
  const short* bP = Bb + (long)(n0 + mloc) * PP + kc * 8;

  f32x4 acc[2][2];
#pragma unroll
  for (int fm = 0; fm < 2; ++fm)
#pragma unroll
    for (int fn = 0; fn < 2; ++fn)
      acc[fm][fn] = (f32x4){0.f, 0.f, 0.f, 0.f};

  gload16(aP, &As[0][tid * 8]);
  gload16(bP, &Bs[0][tid * 8]);
  __syncthreads();

  for (int kt = 0; kt < 8; ++kt) {
    const int cur = kt & 1, nxt = cur ^ 1;
    if (kt < 7) {
      gload16(aP + (kt + 1) * 32, &As[nxt][tid * 8]);
      gload16(bP + (kt + 1) * 32, &Bs[nxt][tid * 8]);
    }
    short8v af[2], bf[2];
#pragma unroll
    for (int fm = 0; fm < 2; ++fm)
      af[fm] = *(const short8v*)&As[cur][(lk * BM + wr * 32 + fm * 16 + lr) * 8];
#pragma unroll
    for (int fn = 0; fn < 2; ++fn)
      bf[fn] = *(const short8v*)&Bs[cur][(lk * BN + wc * 32 + fn * 16 + lr) * 8];
#pragma unroll
    for (int fm = 0; fm < 2; ++fm)
#pragma unroll
      for (int fn = 0; fn < 2; ++fn)
        acc[fm][fn] = __builtin_amdgcn_mfma_f32_16x16x32_bf16(
            af[fm], bf[fn], acc[fm][fn], 0, 0, 0);
    __syncthreads();
  }

#pragma unroll
  for (int fm = 0; fm < 2; ++fm)
#pragma unroll
    for (int fn = 0; fn < 2; ++fn) {
      const int c = n0 + wc * 32 + fn * 16 + lr;
      const int rb = m0 + wr * 32 + fm * 16 + lk * 4;
#pragma unroll
      for (int j = 0; j < 4; ++j)
        Cb[(long)(rb + j) * PP + c] = acc[fm][fn][j];
    }
}

// ---------------------------------------------------------------------------
__global__ __launch_bounds__(256)
void colsum_bf16(const short* __restrict__ srcT, float* __restrict__ raw)
{
  const int b = blockIdx.y;
  const int w = threadIdx.x >> 6, l = threadIdx.x & 63;
  const int p = blockIdx.x * 4 + w;
  const short* row = srcT + ((long)b * 256 + p) * 1024;
  short8v v1 = *(const short8v*)&row[l * 8];
  short8v v2 = *(const short8v*)&row[(64 + l) * 8];
  float s = 0.f;
#pragma unroll
  for (int j = 0; j < 8; ++j) s += bf2f(v1[j]) + bf2f(v2[j]);
#pragma unroll
  for (int off = 32; off; off >>= 1) s += __shfl_down(s, off);
  if (l == 0) raw[(long)b * 256 + p] = s;
}

__global__ __launch_bounds__(256)
void psum_dot(const short* __restrict__ wp1T, const float* __restrict__ rowsum,
              float* __restrict__ rawP)
{
  __shared__ float rsm[1024];
  const int b = blockIdx.x;
  for (int i = threadIdx.x; i < 1024; i += 256) rsm[i] = rowsum[(long)b * 1024 + i];
  __syncthreads();
  const int p = threadIdx.x;
  const short* wrow = wp1T + (long)p * 1024;
  float s = 0.f;
  for (int k = 0; k < 1024; k += 8) {
    short8v v = *(const short8v*)&wrow[k];
#pragma unroll
    for (int j = 0; j < 8; ++j) s = fmaf(bf2f(v[j]), rsm[k + j], s);
  }
  rawP[(long)b * 256 + p] = s;
}

__device__ inline void block_reduce2(float& v1, float& v2, float* red)
{
#pragma unroll
  for (int off = 32; off > 0; off >>= 1) {
    v1 += __shfl_down(v1, off);
    v2 += __shfl_down(v2, off);
  }
  const int lane = threadIdx.x & 63, wid = threadIdx.x >> 6;
  if (lane == 0) { red[wid * 2] = v1; red[wid * 2 + 1] = v2; }
  __syncthreads();
  v1 = red[0] + red[2] + red[4] + red[6];
  v2 = red[1] + red[3] + red[5] + red[7];
}

__global__ __launch_bounds__(256)
void norm_sum2(const float* __restrict__ raw2,
               const float* __restrict__ g_os, const float* __restrict__ b_os,
               const float* __restrict__ g_ps, const float* __restrict__ b_ps,
               float* __restrict__ o_sum, float* __restrict__ p_sum)
{
  const int bb = blockIdx.x;
  const bool isP = bb >= 32;
  const int b = bb & 31;
  const float* raw = raw2 + (isP ? 8192 : 0);
  const float* gamma = isP ? g_ps : g_os;
  const float* beta = isP ? b_ps : b_os;
  float* outp = isP ? p_sum : o_sum;
  const int p = threadIdx.x;
  float s = raw[(long)b * 256 + p];
  __shared__ float red[8];
  float v1 = s, v2 = s * s;
  block_reduce2(v1, v2, red);
  const float mean = v1 / 256.0f;
  float var = fmaxf((v2 - v1 * mean) / 255.0f, 0.f);
  const float inv = 1.0f / (sqrtf(var) + EPSF);
  outp[(long)b * 256 + p] = gamma[p] * (s - mean) * inv + beta[p] + 1.0f;
}

__global__ __launch_bounds__(256)
void stats_dual(const float* __restrict__ t2T, const float* __restrict__ p2,
                float* __restrict__ part)
{
  const int y = blockIdx.y, chunk = blockIdx.x;
  const float* s = (y < 32 ? t2T + ((long)y << 16)
                           : p2 + ((long)(y - 32) << 16)) + (long)chunk * 8192;
  float v1 = 0.f, v2 = 0.f;
  for (int i = threadIdx.x; i < 2048; i += 256) {
    float4 xv = *reinterpret_cast<const float4*>(&s[i * 4]);
    v1 += xv.x + xv.y + xv.z + xv.w;
    v2 = fmaf(xv.x, xv.x, fmaf(xv.y, xv.y, fmaf(xv.z, xv.z, fmaf(xv.w, xv.w, v2))));
  }
  __shared__ float red[8];
  block_reduce2(v1, v2, red);
  if (threadIdx.x == 0) {
    part[(y * 8 + chunk) * 2] = v1;
    part[(y * 8 + chunk) * 2 + 1] = v2;
  }
}

__global__ void stats_fin2(const float* __restrict__ part,
                           float* __restrict__ stO, float* __restrict__ stP)
{
  const int t = threadIdx.x;   // 64
  float v1 = 0.f, v2 = 0.f;
#pragma unroll
  for (int c = 0; c < 8; ++c) {
    v1 += part[(t * 8 + c) * 2];
    v2 += part[(t * 8 + c) * 2 + 1];
  }
  const float mean = v1 / 65536.0f;
  const float var = fmaxf((v2 - v1 * mean) / 65535.0f, 0.f);
  float* st = (t < 32) ? stO : stP;
  st[(t & 31) * 2] = mean;
  st[(t & 31) * 2 + 1] = 1.0f / (sqrtf(var) + EPSF);
}

__global__ __launch_bounds__(256)
void stats_part(const float* __restrict__ src, float* __restrict__ part)
{
  const int b = blockIdx.y, chunk = blockIdx.x;
  const float* s = src + ((long)b << 16) + (long)chunk * 8192;
  float v1 = 0.f, v2 = 0.f;
  for (int i = threadIdx.x; i < 2048; i += 256) {
    float4 xv = *reinterpret_cast<const float4*>(&s[i * 4]);
    v1 += xv.x + xv.y + xv.z + xv.w;
    v2 = fmaf(xv.x, xv.x, fmaf(xv.y, xv.y, fmaf(xv.z, xv.z, fmaf(xv.w, xv.w, v2))));
  }
  __shared__ float red[8];
  block_reduce2(v1, v2, red);
  if (threadIdx.x == 0) {
    part[(b * 8 + chunk) * 2] = v1;
    part[(b * 8 + chunk) * 2 + 1] = v2;
  }
}

__global__ void stats_fin(const float* __restrict__ part, float* __restrict__ st)
{
  const int b = threadIdx.x;
  if (b < 32) {
    float v1 = 0.f, v2 = 0.f;
#pragma unroll
    for (int c = 0; c < 8; ++c) {
      v1 += part[(b * 8 + c) * 2];
      v2 += part[(b * 8 + c) * 2 + 1];
    }
    const float mean = v1 / 65536.0f;
    const float var = fmaxf((v2 - v1 * mean) / 65535.0f, 0.f);
    st[b * 2] = mean;
    st[b * 2 + 1] = 1.0f / (sqrtf(var) + EPSF);
  }
}

__global__ __launch_bounds__(256)
void prep2(const float* __restrict__ t2T, const float* __restrict__ p2,
           const float* __restrict__ o_sum, const float* __restrict__ p_sum,
           const float* __restrict__ gamma_o, const float* __restrict__ beta_o,
           const float* __restrict__ gTp, const float* __restrict__ bTp,
           const float* __restrict__ stO, const float* __restrict__ stP,
           short* __restrict__ Ap, short* __restrict__ BpT,
           float* __restrict__ out)
{
  const long idx = (long)blockIdx.x * 256 + threadIdx.x;
  const int b = (int)(idx >> 16);
  const int rc = (int)(idx & 65535);
  const int r = rc >> 8, c = rc & 255;
  const float mO = stO[b * 2], iO = stO[b * 2 + 1];
  const float mP = stP[b * 2], iP = stP[b * 2 + 1];
  const float relA = o_sum[(b << 8) + r] * p_sum[(b << 8) + c];
  const float on = gamma_o[rc] * (t2T[idx] - mO) * iO + beta_o[rc];
  Ap[idx] = f2bf(on * relA);
  const float pn = gTp[rc] * (p2[idx] - mP) * iP + bTp[rc];
  BpT[idx] = f2bf(pn * o_sum[(b << 8) + c] * p_sum[(b << 8) + r]);
  out[(long)BB * 65536 + idx] = relA;
}

__global__ __launch_bounds__(256)
void final_half(const float* __restrict__ proj, const float* __restrict__ stF,
                const float* __restrict__ gamma, const float* __restrict__ beta,
                float* __restrict__ out)
{
  const long idx = (long)blockIdx.x * 256 + threadIdx.x;
  const int b = (int)(idx >> 16);
  const int ij = (int)(idx & 65535);
  out[idx] = gamma[ij] * (proj[idx] - stF[b * 2]) * stF[b * 2 + 1] + beta[ij];
}

extern "C" void kernel_launch(void* const* d_in, const int* in_sizes, int n_in,
                              void* d_out, int out_size, void* d_ws, size_t ws_size,
                              hipStream_t stream)
{
  const float* x    = (const float*)d_in[0];
  const float* Wo1  = (const float*)d_in[1];
  const float* Wo2  = (const float*)d_in[2];
  const float* Wp1  = (const float*)d_in[3];
  const float* Wp2  = (const float*)d_in[4];
  const float* g_os = (const float*)d_in[5];
  const float* g_o  = (const float*)d_in[6];
  const float* g_ps = (const float*)d_in[7];
  const float* g_p  = (const float*)d_in[8];
  const float* g    = (const float*)d_in[9];
  const float* b_os = (const float*)d_in[10];
  const float* b_o  = (const float*)d_in[11];
  const float* b_ps = (const float*)d_in[12];
  const float* b_p  = (const float*)d_in[13];
  const float* b_   = (const float*)d_in[14];
  float* out = (float*)d_out;

  short* wcat = (short*)d_ws;            // [512][1024] = wo1T ; wp2T
  short* wo2T = wcat + 524288;
  short* wp1T = wo2T + 262144;
  short* oyyT = wp1T + 262144;           // [B][256][1024]
  short* UT   = oyyT + 8388608;          // [B][256][1024]
  float* gTp  = (float*)(UT + 8388608);
  float* bTp  = gTp + 65536;
  float* rowsumX = bTp + 65536;          // [B][1024]
  float* t2T  = rowsumX + 32768;         // [B][256][256]
  float* p2   = t2T + 2097152;
  float* proj = p2 + 2097152;
  short* Ap   = (short*)(proj + 2097152);
  short* BpT  = Ap + 2097152;
  float* raw2 = (float*)(BpT + 2097152); // [2][32][256]
  float* o_sum = raw2 + 16384;
  float* p_sum = o_sum + 8192;
  float* part  = p_sum + 8192;           // [64][8][2]
  float* partF = part + 1024;            // [32][8][2]
  float* stO   = partF + 512;
  float* stP   = stO + 64;
  float* stF   = stP + 64;

  wconv4<<<dim3(4, 16, 4), 256, 0, stream>>>(Wo1, Wo2, Wp1, Wp2,
                                             wcat, wo2T, wp1T, wcat + 262144);
  tr2_f32<<<dim3(4, 4, 2), 256, 0, stream>>>(g_p, b_p, gTp, bTp);

  gemm_xcat<<<dim3(8, 4, 32), 256, 0, stream>>>(x, wcat, oyyT, UT, rowsumX);

  colsum_bf16<<<dim3(64, 32), 256, 0, stream>>>(oyyT, raw2);
  psum_dot<<<32, 256, 0, stream>>>(wp1T, rowsumX, raw2 + 8192);
  norm_sum2<<<64, 256, 0, stream>>>(raw2, g_os, b_os, g_ps, b_ps, o_sum, p_sum);

  gemm_dual<<<dim3(4, 4, 64), 256, 0, stream>>>(oyyT, wo2T, UT, wp1T, t2T, p2);

  stats_dual<<<dim3(8, 64), 256, 0, stream>>>(t2T, p2, part);
  stats_fin2<<<1, 64, 0, stream>>>(part, stO, stP);

  prep2<<<8192, 256, 0, stream>>>(t2T, p2, o_sum, p_sum, g_o, b_o, gTp, bTp,
                                  stO, stP, Ap, BpT, out);

  gemm_pp<<<dim3(4, 4, 32), 256, 0, stream>>>(Ap, BpT, proj);

  stats_part<<<dim3(8, 32), 256, 0, stream>>>(proj, partF);
  stats_fin<<<1, 64, 0, stream>>>(partF, stF);

  final_half<<<8192, 256, 0, stream>>>(proj, stF, g, b_, out);
}